// Round 7
// baseline (880.611 us; speedup 1.0000x reference)
//
#include <hip/hip_runtime.h>
#include <math.h>

// ---------------- problem constants ----------------
#define B_    8
#define H_    56
#define W_    56
#define HW_   3136
#define C0_   256
#define C1_   512
#define C2_   1024
#define DIN_  1794      // raw conv_w K (includes 2 coord cols, folded into epilogue)
#define KD_   1792      // descriptor K (GEMM K), 56 chunks of 32
#define KCP_  56        // phi K-chunks
#define DOUT_ 448
#define NCHP_ 28        // phi N-chunks (448/16)
#define NC_   3136      // centers
#define NCHD_ 196       // dist N-chunks (3136/16)
#define KCD_  14        // dist K-chunks (448/32)
#define DTS_  452       // LDS D-tile row stride (floats)
#define PCH_  28672     // phip chunk stride in shorts (in-place alias of desc pixels)

typedef __attribute__((ext_vector_type(8))) short bh8;
typedef __attribute__((ext_vector_type(4))) float f32x4;

__device__ __forceinline__ short f2bf(float f) {
  union { float f; unsigned u; } v; v.f = f;
  unsigned r = v.u + 0x7fffu + ((v.u >> 16) & 1u);
  return (short)(r >> 16);
}
__device__ __forceinline__ float bf2f(short s) {
  union { unsigned u; float f; } v; v.u = ((unsigned)(unsigned short)s) << 16;
  return v.f;
}

// ======== desc0: pool(p0) -> desc[:, 0:256], transposed, bf16 ========
__global__ __launch_bounds__(256) void desc0_kernel(const float* __restrict__ p0,
                                                    short* __restrict__ desc) {
  __shared__ float sv[64 * 57];
  const int c0 = blockIdx.x * 64, h = blockIdx.y, b = blockIdx.z;
  for (int item = threadIdx.x; item < 64 * 56; item += 256) {
    int x = item % 56, c = item / 56;
    const float* src = p0 + (((size_t)(b * C0_ + c0 + c)) * 56 + h) * 56 + x;
    float s = src[0];
    if (h > 0)  s += src[-56];
    if (h < 55) s += src[56];
    sv[c * 57 + x] = s;
  }
  __syncthreads();
  for (int item = threadIdx.x; item < 56 * 8; item += 256) {
    int g = item & 7, w = item >> 3;
    bh8 o;
#pragma unroll
    for (int j = 0; j < 8; ++j) {
      const float* s0 = sv + (g * 8 + j) * 57;
      float v = s0[w];
      if (w > 0)  v += s0[w - 1];
      if (w < 55) v += s0[w + 1];
      o[j] = f2bf(v * (1.0f / 9.0f));
    }
    size_t pid = (size_t)b * HW_ + h * 56 + w;
    *(bh8*)(desc + pid * KD_ + c0 + g * 8) = o;
  }
}

// ======== desc1: pool(p1)+bilinear x2 -> desc[:, 256:768] ========
__global__ __launch_bounds__(256) void desc1_kernel(const float* __restrict__ p1,
                                                    short* __restrict__ desc) {
  __shared__ float sv[2 * 64 * 29];
  const int c0 = blockIdx.x * 64, h = blockIdx.y, b = blockIdx.z;
  float sy = (h + 0.5f) * 0.5f - 0.5f;
  float fyf = floorf(sy);
  float fy = sy - fyf;
  int iy = (int)fyf;
  int pya = min(max(iy, 0), 27), pyb = min(max(iy + 1, 0), 27);
  for (int item = threadIdx.x; item < 64 * 2 * 28; item += 256) {
    int x = item % 28;
    int pr = (item / 28) & 1;
    int c = item / 56;
    int r = pr ? pyb : pya;
    const float* src = p1 + (((size_t)(b * C1_ + c0 + c)) * 28 + r) * 28 + x;
    float s = src[0];
    if (r > 0)  s += src[-28];
    if (r < 27) s += src[28];
    sv[pr * (64 * 29) + c * 29 + x] = s;
  }
  __syncthreads();
  for (int item = threadIdx.x; item < 56 * 8; item += 256) {
    int g = item & 7, w = item >> 3;
    float sx = (w + 0.5f) * 0.5f - 0.5f;
    float fxf = floorf(sx);
    float fx = sx - fxf;
    int ix = (int)fxf;
    int x0 = min(max(ix, 0), 27), x1 = min(max(ix + 1, 0), 27);
    bh8 o;
#pragma unroll
    for (int j = 0; j < 8; ++j) {
      const float* s0 = sv + (g * 8 + j) * 29;
      const float* s1 = s0 + 64 * 29;
      float p00 = s0[x0] + (x0 > 0 ? s0[x0 - 1] : 0.f) + (x0 < 27 ? s0[x0 + 1] : 0.f);
      float p01 = s0[x1] + (x1 > 0 ? s0[x1 - 1] : 0.f) + (x1 < 27 ? s0[x1 + 1] : 0.f);
      float p10 = s1[x0] + (x0 > 0 ? s1[x0 - 1] : 0.f) + (x0 < 27 ? s1[x0 + 1] : 0.f);
      float p11 = s1[x1] + (x1 > 0 ? s1[x1 - 1] : 0.f) + (x1 < 27 ? s1[x1 + 1] : 0.f);
      float top = p00 + fx * (p01 - p00);
      float bot = p10 + fx * (p11 - p10);
      o[j] = f2bf((top + fy * (bot - top)) * (1.0f / 9.0f));
    }
    size_t pid = (size_t)b * HW_ + h * 56 + w;
    *(bh8*)(desc + pid * KD_ + C0_ + c0 + g * 8) = o;
  }
}

// ======== desc2: pool(p2)+bilinear x4 -> desc[:, 768:1792] ========
__global__ __launch_bounds__(256) void desc2_kernel(const float* __restrict__ p2,
                                                    short* __restrict__ desc) {
  __shared__ float sv[2 * 64 * 15];
  const int c0 = blockIdx.x * 64, h = blockIdx.y, b = blockIdx.z;
  float sy = (h + 0.5f) * 0.25f - 0.5f;
  float fyf = floorf(sy);
  float fy = sy - fyf;
  int iy = (int)fyf;
  int pya = min(max(iy, 0), 13), pyb = min(max(iy + 1, 0), 13);
  for (int item = threadIdx.x; item < 64 * 2 * 14; item += 256) {
    int x = item % 14;
    int pr = (item / 14) & 1;
    int c = item / 28;
    int r = pr ? pyb : pya;
    const float* src = p2 + (((size_t)(b * C2_ + c0 + c)) * 14 + r) * 14 + x;
    float s = src[0];
    if (r > 0)  s += src[-14];
    if (r < 13) s += src[14];
    sv[pr * (64 * 15) + c * 15 + x] = s;
  }
  __syncthreads();
  for (int item = threadIdx.x; item < 56 * 8; item += 256) {
    int g = item & 7, w = item >> 3;
    float sx = (w + 0.5f) * 0.25f - 0.5f;
    float fxf = floorf(sx);
    float fx = sx - fxf;
    int ix = (int)fxf;
    int x0 = min(max(ix, 0), 13), x1 = min(max(ix + 1, 0), 13);
    bh8 o;
#pragma unroll
    for (int j = 0; j < 8; ++j) {
      const float* s0 = sv + (g * 8 + j) * 15;
      const float* s1 = s0 + 64 * 15;
      float p00 = s0[x0] + (x0 > 0 ? s0[x0 - 1] : 0.f) + (x0 < 13 ? s0[x0 + 1] : 0.f);
      float p01 = s0[x1] + (x1 > 0 ? s0[x1 - 1] : 0.f) + (x1 < 13 ? s0[x1 + 1] : 0.f);
      float p10 = s1[x0] + (x0 > 0 ? s1[x0 - 1] : 0.f) + (x0 < 13 ? s1[x0 + 1] : 0.f);
      float p11 = s1[x1] + (x1 > 0 ? s1[x1 - 1] : 0.f) + (x1 < 13 ? s1[x1 + 1] : 0.f);
      float top = p00 + fx * (p01 - p00);
      float bot = p10 + fx * (p11 - p10);
      o[j] = f2bf((top + fy * (bot - top)) * (1.0f / 9.0f));
    }
    size_t pid = (size_t)b * HW_ + h * 56 + w;
    *(bh8*)(desc + pid * KD_ + C0_ + C1_ + c0 + g * 8) = o;
  }
}

// ---------------- |c_j|^2 from bf16-rounded C ----------------
__global__ void cent2_kernel(const float* __restrict__ C, float* __restrict__ c2) {
  int j = blockIdx.x * blockDim.x + threadIdx.x;
  if (j >= NC_) return;
  float s = 0.f;
  for (int d = 0; d < DOUT_; ++d) {
    float v = bf2f(f2bf(C[(size_t)d * NC_ + j]));
    s = fmaf(v, v, s);
  }
  c2[j] = s;
}

// ---------------- pack C (K=448 x N=3136) into B-frag layout ----------------
__global__ void cpack_kernel(const float* __restrict__ C, short* __restrict__ Cpk) {
  int idx = blockIdx.x * 256 + threadIdx.x;       // NCHD_*KCD_*64 = 175616 exact
  int ln = idx & 63;
  int kc = (idx >> 6) % KCD_;
  int nc = idx / (KCD_ * 64);
  int n  = nc * 16 + (ln & 15);
  int k0 = kc * 32 + ((ln >> 4) << 3);
  bh8 o;
#pragma unroll
  for (int j = 0; j < 8; ++j) o[j] = f2bf(C[(size_t)(k0 + j) * NC_ + n]);
  *(bh8*)(Cpk + (size_t)idx * 8) = o;
}

// ---------------- pack W^T (K=1792 x N=448) into B-frag layout ----------------
__global__ void wpack_kernel(const float* __restrict__ W, short* __restrict__ Wpk) {
  int idx = blockIdx.x * 256 + threadIdx.x;       // NCHP_*KCP_*64 = 100352 exact
  int ln = idx & 63;
  int kc = (idx >> 6) % KCP_;
  int nc = idx / (KCP_ * 64);
  int n  = nc * 16 + (ln & 15);
  int k0 = kc * 32 + ((ln >> 4) << 3);
  bh8 o;
#pragma unroll
  for (int j = 0; j < 8; ++j) o[j] = f2bf(W[(size_t)n * DIN_ + k0 + j]);
  *(bh8*)(Wpk + (size_t)idx * 8) = o;
}

// ======== phi: A-frags direct from desc; bias+coords fused; in-place phipack ========
__global__ __launch_bounds__(256) void phi_mfma(
    const short* __restrict__ desc, const short* __restrict__ Wpk,
    const float* __restrict__ cw, const float* __restrict__ cb,
    short* __restrict__ phip /* aliases desc */) {
  __shared__ __align__(16) float Dt[16 * DTS_];   // 28.9 KB
  const int wv = threadIdx.x >> 6, ln = threadIdx.x & 63;
  const int pix0 = blockIdx.x * 32;
  const short* aptr = desc + ((size_t)(pix0 + (ln & 15))) * KD_ + ((ln >> 4) << 3);

  f32x4 acc[2][7];
#pragma unroll
  for (int rc = 0; rc < 2; ++rc)
#pragma unroll
    for (int i = 0; i < 7; ++i) acc[rc][i] = (f32x4){0.f, 0.f, 0.f, 0.f};

  const short* bbase = Wpk + (size_t)(wv * 7) * (KCP_ * 512) + ln * 8;
  for (int kc = 0; kc < KCP_; ++kc) {
    bh8 a0 = *(const bh8*)(aptr + kc * 32);
    bh8 a1 = *(const bh8*)(aptr + 16 * KD_ + kc * 32);
    const short* bp = bbase + kc * 512;
#pragma unroll
    for (int i = 0; i < 7; ++i) {
      bh8 bfr = *(const bh8*)(bp + (size_t)i * (KCP_ * 512));
      acc[0][i] = __builtin_amdgcn_mfma_f32_16x16x32_bf16(a0, bfr, acc[0][i], 0, 0, 0);
      acc[1][i] = __builtin_amdgcn_mfma_f32_16x16x32_bf16(a1, bfr, acc[1][i], 0, 0, 0);
    }
  }

  for (int rc = 0; rc < 2; ++rc) {
    __syncthreads();   // rc=0: all desc reads done; rc=1: all rc=0 repack reads done
#pragma unroll
    for (int i = 0; i < 7; ++i) {
      int col = (wv * 7 + i) * 16 + (ln & 15);
      float bias = cb[col];
      float wx = cw[(size_t)col * DIN_ + 1792];
      float wy = cw[(size_t)col * DIN_ + 1793];
#pragma unroll
      for (int r = 0; r < 4; ++r) {
        int row = ((ln >> 4) << 2) + r;
        int pid = pix0 + rc * 16 + row;
        int hw = pid % HW_;
        int hh = hw / 56, ww = hw % 56;
        float xx = (float)hh * (2.0f / 55.0f) - 1.0f;
        float yy = (float)ww * (2.0f / 55.0f) - 1.0f;
        Dt[row * DTS_ + col] = acc[rc][i][r] + bias + wx * xx + wy * yy;
      }
    }
    __syncthreads();
    short* op = phip + (size_t)(blockIdx.x * 2 + rc) * PCH_;
    for (int item = threadIdx.x; item < KCD_ * 64; item += 256) {
      int kc = item >> 6, lp = item & 63;
      int m = lp & 15, k0 = kc * 32 + ((lp >> 4) << 3);
      bh8 o;
#pragma unroll
      for (int j = 0; j < 8; ++j) o[j] = f2bf(Dt[m * DTS_ + k0 + j]);
      *(bh8*)(op + (size_t)item * 8) = o;
    }
  }
}

// ======== dist v5: block = 32 px; A-frags staged in LDS (spill-proof) ========
// 4 waves split 196 N-chunks (49 each); per K-step: 1 global B-frag +
// 2 LDS A-frags + 2 MFMAs. No register arrays live across loops.
__device__ __forceinline__ void insert3(float& t0, float& t1, float& t2, float v) {
  if (v < t2) {
    if (v < t1) {
      t2 = t1;
      if (v < t0) { t1 = t0; t0 = v; } else t1 = v;
    } else t2 = v;
  }
}
__device__ __forceinline__ void merge3(float& a0, float& a1, float& a2,
                                       float b0, float b1, float b2) {
  float lo0 = fminf(a0, b0), hi0 = fmaxf(a0, b0);
  float lo1 = fminf(a1, b1), hi1 = fmaxf(a1, b1);
  float lo2 = fminf(a2, b2);
  a0 = lo0;
  a1 = fminf(hi0, lo1);
  a2 = fminf(fmaxf(hi0, lo1), fminf(hi1, lo2));
}

__global__ __launch_bounds__(256) void dist_mfma(
    const short* __restrict__ phip, const short* __restrict__ Cpk,
    const float* __restrict__ c2g, float* __restrict__ out) {
  __shared__ __align__(16) short sA[2 * KCD_ * 64 * 8];   // 28 KB: 2 chunks of A-frags
  __shared__ float mb[4][32][3];
  const int wv = threadIdx.x >> 6, ln = threadIdx.x & 63;
  const int chunk0 = blockIdx.x * 2;

  // stage both 16-pixel chunks' A-frags (byte-identical copy of phipack layout)
  for (int item = threadIdx.x; item < 2 * KCD_ * 64; item += 256) {
    int c = item / (KCD_ * 64), off = item - c * (KCD_ * 64);
    *(bh8*)(sA + (size_t)item * 8) =
        *(const bh8*)(phip + (size_t)(chunk0 + c) * PCH_ + (size_t)off * 8);
  }
  __syncthreads();

  // f2 per pixel row (self-consistent with bf16 MFMA dot)
  float f2r[2][4];
#pragma unroll
  for (int rc = 0; rc < 2; ++rc) {
    float sum = 0.f;
#pragma unroll
    for (int kc = 0; kc < KCD_; ++kc) {
      bh8 a = *(const bh8*)(sA + (size_t)(rc * (KCD_ * 64) + kc * 64 + ln) * 8);
#pragma unroll
      for (int j = 0; j < 8; ++j) { float v = bf2f(a[j]); sum = fmaf(v, v, sum); }
    }
    sum += __shfl_xor(sum, 16, 64);
    sum += __shfl_xor(sum, 32, 64);
#pragma unroll
    for (int r = 0; r < 4; ++r) f2r[rc][r] = __shfl(sum, ((ln >> 4) << 2) + r, 64);
  }

  float t3[2][4][3];
#pragma unroll
  for (int rc = 0; rc < 2; ++rc)
#pragma unroll
    for (int r = 0; r < 4; ++r) { t3[rc][r][0] = 1e30f; t3[rc][r][1] = 1e30f; t3[rc][r][2] = 1e30f; }

  // this wave's 49 N-chunks; B-frag shared by both pixel-chunk MFMA chains
  const short* bbase = Cpk + (size_t)(wv * 49) * (KCD_ * 512) + ln * 8;
  const short* a0base = sA + (size_t)ln * 8;
  const short* a1base = a0base + (size_t)(KCD_ * 64) * 8;
  for (int i = 0; i < 49; ++i) {
    const short* bp = bbase + (size_t)i * (KCD_ * 512);
    f32x4 acc0 = {0.f, 0.f, 0.f, 0.f}, acc1 = {0.f, 0.f, 0.f, 0.f};
#pragma unroll
    for (int kc = 0; kc < KCD_; ++kc) {
      bh8 b  = *(const bh8*)(bp + kc * 512);
      bh8 a0 = *(const bh8*)(a0base + (size_t)kc * 512);
      bh8 a1 = *(const bh8*)(a1base + (size_t)kc * 512);
      acc0 = __builtin_amdgcn_mfma_f32_16x16x32_bf16(a0, b, acc0, 0, 0, 0);
      acc1 = __builtin_amdgcn_mfma_f32_16x16x32_bf16(a1, b, acc1, 0, 0, 0);
    }
    int nc = wv * 49 + i;
    float c2v = c2g[nc * 16 + (ln & 15)];
#pragma unroll
    for (int r = 0; r < 4; ++r) {
      insert3(t3[0][r][0], t3[0][r][1], t3[0][r][2], f2r[0][r] + c2v - 2.0f * acc0[r]);
      insert3(t3[1][r][0], t3[1][r][1], t3[1][r][2], f2r[1][r] + c2v - 2.0f * acc1[r]);
    }
  }

  // merge the 16 column-lanes (same pixel rows, different centers)
#pragma unroll
  for (int m = 1; m <= 8; m <<= 1) {
#pragma unroll
    for (int rc = 0; rc < 2; ++rc)
#pragma unroll
      for (int r = 0; r < 4; ++r) {
        float b0 = __shfl_xor(t3[rc][r][0], m, 64);
        float b1 = __shfl_xor(t3[rc][r][1], m, 64);
        float b2 = __shfl_xor(t3[rc][r][2], m, 64);
        merge3(t3[rc][r][0], t3[rc][r][1], t3[rc][r][2], b0, b1, b2);
      }
  }

  // cross-wave merge (waves hold disjoint center ranges for the same 32 pixels)
  if ((ln & 15) == 0) {
#pragma unroll
    for (int rc = 0; rc < 2; ++rc)
#pragma unroll
      for (int r = 0; r < 4; ++r) {
        int row = rc * 16 + ((ln >> 4) << 2) + r;
        mb[wv][row][0] = t3[rc][r][0];
        mb[wv][row][1] = t3[rc][r][1];
        mb[wv][row][2] = t3[rc][r][2];
      }
  }
  __syncthreads();
  if (threadIdx.x < 32) {
    int row = threadIdx.x;
    float a0 = mb[0][row][0], a1 = mb[0][row][1], a2 = mb[0][row][2];
#pragma unroll
    for (int w2 = 1; w2 < 4; ++w2) merge3(a0, a1, a2, mb[w2][row][0], mb[w2][row][1], mb[w2][row][2]);
    float d0 = sqrtf(fmaxf(a0, 0.f));
    float d1 = sqrtf(fmaxf(a1, 0.f));
    float d2 = sqrtf(fmaxf(a2, 0.f));
    float s0 = 1.0f / (1.0f + expf(d0 - d1) + expf(d0 - d2));
    out[chunk0 * 16 + row] = s0 * d0;
  }
}

// ---------------- launch ----------------
extern "C" void kernel_launch(void* const* d_in, const int* in_sizes, int n_in,
                              void* d_out, int out_size, void* d_ws, size_t ws_size,
                              hipStream_t stream) {
  const float* p0 = (const float*)d_in[0];
  const float* p1 = (const float*)d_in[1];
  const float* p2 = (const float*)d_in[2];
  const float* cw = (const float*)d_in[3];
  const float* cb = (const float*)d_in[4];
  const float* C  = (const float*)d_in[5];
  float* out = (float*)d_out;

  short* desc = (short*)d_ws;
  short* Cpk  = desc + (size_t)25088 * KD_;
  short* Wpk  = Cpk + (size_t)NCHD_ * KCD_ * 512;
  float* c2   = (float*)(Wpk + (size_t)NCHP_ * KCP_ * 512);

  desc0_kernel<<<dim3(4, 56, 8),  256, 0, stream>>>(p0, desc);
  desc1_kernel<<<dim3(8, 56, 8),  256, 0, stream>>>(p1, desc);
  desc2_kernel<<<dim3(16, 56, 8), 256, 0, stream>>>(p2, desc);
  cent2_kernel<<<(NC_ + 255) / 256, 256, 0, stream>>>(C, c2);
  cpack_kernel<<<NCHD_ * KCD_ * 64 / 256, 256, 0, stream>>>(C, Cpk);
  wpack_kernel<<<NCHP_ * KCP_ * 64 / 256, 256, 0, stream>>>(cw, Wpk);
  phi_mfma<<<25088 / 32, 256, 0, stream>>>(desc, Wpk, cw, cb, desc);
  dist_mfma<<<25088 / 32, 256, 0, stream>>>(desc, Cpk, c2, out);
}

// Round 8
// 815.234 us; speedup vs baseline: 1.0802x; 1.0802x over previous
//
#include <hip/hip_runtime.h>
#include <math.h>

// ---------------- problem constants ----------------
#define B_    8
#define H_    56
#define W_    56
#define HW_   3136
#define C0_   256
#define C1_   512
#define C2_   1024
#define DIN_  1794      // raw conv_w K (includes 2 coord cols, folded into epilogue)
#define KD_   1792      // descriptor K (GEMM K), 56 chunks of 32
#define KCP_  56        // phi K-chunks
#define DOUT_ 448
#define NCHP_ 28        // phi N-chunks (448/16)
#define NC_   3136      // centers
#define NCHD_ 196       // dist N-chunks (3136/16)
#define KCD_  14        // dist K-chunks (448/32)
#define DTS_  452       // LDS D-tile row stride (floats)
#define PCH_  28672     // phip chunk stride in shorts (in-place alias of desc pixels)

typedef __attribute__((ext_vector_type(8))) short bh8;
typedef __attribute__((ext_vector_type(4))) float f32x4;

__device__ __forceinline__ short f2bf(float f) {
  union { float f; unsigned u; } v; v.f = f;
  unsigned r = v.u + 0x7fffu + ((v.u >> 16) & 1u);
  return (short)(r >> 16);
}
__device__ __forceinline__ float bf2f(short s) {
  union { unsigned u; float f; } v; v.u = ((unsigned)(unsigned short)s) << 16;
  return v.f;
}

// ======== desc0: pool(p0) -> desc[:, 0:256], transposed, bf16 ========
__global__ __launch_bounds__(256) void desc0_kernel(const float* __restrict__ p0,
                                                    short* __restrict__ desc) {
  __shared__ float sv[64 * 57];
  const int c0 = blockIdx.x * 64, h = blockIdx.y, b = blockIdx.z;
  for (int item = threadIdx.x; item < 64 * 56; item += 256) {
    int x = item % 56, c = item / 56;
    const float* src = p0 + (((size_t)(b * C0_ + c0 + c)) * 56 + h) * 56 + x;
    float s = src[0];
    if (h > 0)  s += src[-56];
    if (h < 55) s += src[56];
    sv[c * 57 + x] = s;
  }
  __syncthreads();
  for (int item = threadIdx.x; item < 56 * 8; item += 256) {
    int g = item & 7, w = item >> 3;
    bh8 o;
#pragma unroll
    for (int j = 0; j < 8; ++j) {
      const float* s0 = sv + (g * 8 + j) * 57;
      float v = s0[w];
      if (w > 0)  v += s0[w - 1];
      if (w < 55) v += s0[w + 1];
      o[j] = f2bf(v * (1.0f / 9.0f));
    }
    size_t pid = (size_t)b * HW_ + h * 56 + w;
    *(bh8*)(desc + pid * KD_ + c0 + g * 8) = o;
  }
}

// ======== desc1: pool(p1)+bilinear x2 -> desc[:, 256:768] ========
__global__ __launch_bounds__(256) void desc1_kernel(const float* __restrict__ p1,
                                                    short* __restrict__ desc) {
  __shared__ float sv[2 * 64 * 29];
  const int c0 = blockIdx.x * 64, h = blockIdx.y, b = blockIdx.z;
  float sy = (h + 0.5f) * 0.5f - 0.5f;
  float fyf = floorf(sy);
  float fy = sy - fyf;
  int iy = (int)fyf;
  int pya = min(max(iy, 0), 27), pyb = min(max(iy + 1, 0), 27);
  for (int item = threadIdx.x; item < 64 * 2 * 28; item += 256) {
    int x = item % 28;
    int pr = (item / 28) & 1;
    int c = item / 56;
    int r = pr ? pyb : pya;
    const float* src = p1 + (((size_t)(b * C1_ + c0 + c)) * 28 + r) * 28 + x;
    float s = src[0];
    if (r > 0)  s += src[-28];
    if (r < 27) s += src[28];
    sv[pr * (64 * 29) + c * 29 + x] = s;
  }
  __syncthreads();
  for (int item = threadIdx.x; item < 56 * 8; item += 256) {
    int g = item & 7, w = item >> 3;
    float sx = (w + 0.5f) * 0.5f - 0.5f;
    float fxf = floorf(sx);
    float fx = sx - fxf;
    int ix = (int)fxf;
    int x0 = min(max(ix, 0), 27), x1 = min(max(ix + 1, 0), 27);
    bh8 o;
#pragma unroll
    for (int j = 0; j < 8; ++j) {
      const float* s0 = sv + (g * 8 + j) * 29;
      const float* s1 = s0 + 64 * 29;
      float p00 = s0[x0] + (x0 > 0 ? s0[x0 - 1] : 0.f) + (x0 < 27 ? s0[x0 + 1] : 0.f);
      float p01 = s0[x1] + (x1 > 0 ? s0[x1 - 1] : 0.f) + (x1 < 27 ? s0[x1 + 1] : 0.f);
      float p10 = s1[x0] + (x0 > 0 ? s1[x0 - 1] : 0.f) + (x0 < 27 ? s1[x0 + 1] : 0.f);
      float p11 = s1[x1] + (x1 > 0 ? s1[x1 - 1] : 0.f) + (x1 < 27 ? s1[x1 + 1] : 0.f);
      float top = p00 + fx * (p01 - p00);
      float bot = p10 + fx * (p11 - p10);
      o[j] = f2bf((top + fy * (bot - top)) * (1.0f / 9.0f));
    }
    size_t pid = (size_t)b * HW_ + h * 56 + w;
    *(bh8*)(desc + pid * KD_ + C0_ + c0 + g * 8) = o;
  }
}

// ======== desc2: pool(p2)+bilinear x4 -> desc[:, 768:1792] ========
__global__ __launch_bounds__(256) void desc2_kernel(const float* __restrict__ p2,
                                                    short* __restrict__ desc) {
  __shared__ float sv[2 * 64 * 15];
  const int c0 = blockIdx.x * 64, h = blockIdx.y, b = blockIdx.z;
  float sy = (h + 0.5f) * 0.25f - 0.5f;
  float fyf = floorf(sy);
  float fy = sy - fyf;
  int iy = (int)fyf;
  int pya = min(max(iy, 0), 13), pyb = min(max(iy + 1, 0), 13);
  for (int item = threadIdx.x; item < 64 * 2 * 14; item += 256) {
    int x = item % 14;
    int pr = (item / 14) & 1;
    int c = item / 28;
    int r = pr ? pyb : pya;
    const float* src = p2 + (((size_t)(b * C2_ + c0 + c)) * 14 + r) * 14 + x;
    float s = src[0];
    if (r > 0)  s += src[-14];
    if (r < 13) s += src[14];
    sv[pr * (64 * 15) + c * 15 + x] = s;
  }
  __syncthreads();
  for (int item = threadIdx.x; item < 56 * 8; item += 256) {
    int g = item & 7, w = item >> 3;
    float sx = (w + 0.5f) * 0.25f - 0.5f;
    float fxf = floorf(sx);
    float fx = sx - fxf;
    int ix = (int)fxf;
    int x0 = min(max(ix, 0), 13), x1 = min(max(ix + 1, 0), 13);
    bh8 o;
#pragma unroll
    for (int j = 0; j < 8; ++j) {
      const float* s0 = sv + (g * 8 + j) * 15;
      const float* s1 = s0 + 64 * 15;
      float p00 = s0[x0] + (x0 > 0 ? s0[x0 - 1] : 0.f) + (x0 < 13 ? s0[x0 + 1] : 0.f);
      float p01 = s0[x1] + (x1 > 0 ? s0[x1 - 1] : 0.f) + (x1 < 13 ? s0[x1 + 1] : 0.f);
      float p10 = s1[x0] + (x0 > 0 ? s1[x0 - 1] : 0.f) + (x0 < 13 ? s1[x0 + 1] : 0.f);
      float p11 = s1[x1] + (x1 > 0 ? s1[x1 - 1] : 0.f) + (x1 < 13 ? s1[x1 + 1] : 0.f);
      float top = p00 + fx * (p01 - p00);
      float bot = p10 + fx * (p11 - p10);
      o[j] = f2bf((top + fy * (bot - top)) * (1.0f / 9.0f));
    }
    size_t pid = (size_t)b * HW_ + h * 56 + w;
    *(bh8*)(desc + pid * KD_ + C0_ + C1_ + c0 + g * 8) = o;
  }
}

// ---------------- |c_j|^2 from bf16-rounded C ----------------
__global__ void cent2_kernel(const float* __restrict__ C, float* __restrict__ c2) {
  int j = blockIdx.x * blockDim.x + threadIdx.x;
  if (j >= NC_) return;
  float s = 0.f;
  for (int d = 0; d < DOUT_; ++d) {
    float v = bf2f(f2bf(C[(size_t)d * NC_ + j]));
    s = fmaf(v, v, s);
  }
  c2[j] = s;
}

// ---------------- pack C (K=448 x N=3136) into B-frag layout ----------------
__global__ void cpack_kernel(const float* __restrict__ C, short* __restrict__ Cpk) {
  int idx = blockIdx.x * 256 + threadIdx.x;       // NCHD_*KCD_*64 = 175616 exact
  int ln = idx & 63;
  int kc = (idx >> 6) % KCD_;
  int nc = idx / (KCD_ * 64);
  int n  = nc * 16 + (ln & 15);
  int k0 = kc * 32 + ((ln >> 4) << 3);
  bh8 o;
#pragma unroll
  for (int j = 0; j < 8; ++j) o[j] = f2bf(C[(size_t)(k0 + j) * NC_ + n]);
  *(bh8*)(Cpk + (size_t)idx * 8) = o;
}

// ---------------- pack W^T (K=1792 x N=448) into B-frag layout ----------------
__global__ void wpack_kernel(const float* __restrict__ W, short* __restrict__ Wpk) {
  int idx = blockIdx.x * 256 + threadIdx.x;       // NCHP_*KCP_*64 = 100352 exact
  int ln = idx & 63;
  int kc = (idx >> 6) % KCP_;
  int nc = idx / (KCP_ * 64);
  int n  = nc * 16 + (ln & 15);
  int k0 = kc * 32 + ((ln >> 4) << 3);
  bh8 o;
#pragma unroll
  for (int j = 0; j < 8; ++j) o[j] = f2bf(W[(size_t)n * DIN_ + k0 + j]);
  *(bh8*)(Wpk + (size_t)idx * 8) = o;
}

// ======== phi: A-frags direct from desc; bias+coords fused; in-place phipack ========
__global__ __launch_bounds__(256) void phi_mfma(
    const short* __restrict__ desc, const short* __restrict__ Wpk,
    const float* __restrict__ cw, const float* __restrict__ cb,
    short* __restrict__ phip /* aliases desc */) {
  __shared__ __align__(16) float Dt[16 * DTS_];   // 28.9 KB
  const int wv = threadIdx.x >> 6, ln = threadIdx.x & 63;
  const int pix0 = blockIdx.x * 32;
  const short* aptr = desc + ((size_t)(pix0 + (ln & 15))) * KD_ + ((ln >> 4) << 3);

  f32x4 acc[2][7];
#pragma unroll
  for (int rc = 0; rc < 2; ++rc)
#pragma unroll
    for (int i = 0; i < 7; ++i) acc[rc][i] = (f32x4){0.f, 0.f, 0.f, 0.f};

  const short* bbase = Wpk + (size_t)(wv * 7) * (KCP_ * 512) + ln * 8;
  for (int kc = 0; kc < KCP_; ++kc) {
    bh8 a0 = *(const bh8*)(aptr + kc * 32);
    bh8 a1 = *(const bh8*)(aptr + 16 * KD_ + kc * 32);
    const short* bp = bbase + kc * 512;
#pragma unroll
    for (int i = 0; i < 7; ++i) {
      bh8 bfr = *(const bh8*)(bp + (size_t)i * (KCP_ * 512));
      acc[0][i] = __builtin_amdgcn_mfma_f32_16x16x32_bf16(a0, bfr, acc[0][i], 0, 0, 0);
      acc[1][i] = __builtin_amdgcn_mfma_f32_16x16x32_bf16(a1, bfr, acc[1][i], 0, 0, 0);
    }
  }

  for (int rc = 0; rc < 2; ++rc) {
    __syncthreads();   // rc=0: all desc reads done; rc=1: all rc=0 repack reads done
#pragma unroll
    for (int i = 0; i < 7; ++i) {
      int col = (wv * 7 + i) * 16 + (ln & 15);
      float bias = cb[col];
      float wx = cw[(size_t)col * DIN_ + 1792];
      float wy = cw[(size_t)col * DIN_ + 1793];
#pragma unroll
      for (int r = 0; r < 4; ++r) {
        int row = ((ln >> 4) << 2) + r;
        int pid = pix0 + rc * 16 + row;
        int hw = pid % HW_;
        int hh = hw / 56, ww = hw % 56;
        float xx = (float)hh * (2.0f / 55.0f) - 1.0f;
        float yy = (float)ww * (2.0f / 55.0f) - 1.0f;
        Dt[row * DTS_ + col] = acc[rc][i][r] + bias + wx * xx + wy * yy;
      }
    }
    __syncthreads();
    short* op = phip + (size_t)(blockIdx.x * 2 + rc) * PCH_;
    for (int item = threadIdx.x; item < KCD_ * 64; item += 256) {
      int kc = item >> 6, lp = item & 63;
      int m = lp & 15, k0 = kc * 32 + ((lp >> 4) << 3);
      bh8 o;
#pragma unroll
      for (int j = 0; j < 8; ++j) o[j] = f2bf(Dt[m * DTS_ + k0 + j]);
      *(bh8*)(op + (size_t)item * 8) = o;
    }
  }
}

// ======== dist v6: v5 + anti-LICM opaque pointers (loads stay in-loop) ========
__device__ __forceinline__ void insert3(float& t0, float& t1, float& t2, float v) {
  if (v < t2) {
    if (v < t1) {
      t2 = t1;
      if (v < t0) { t1 = t0; t0 = v; } else t1 = v;
    } else t2 = v;
  }
}
__device__ __forceinline__ void merge3(float& a0, float& a1, float& a2,
                                       float b0, float b1, float b2) {
  float lo0 = fminf(a0, b0), hi0 = fmaxf(a0, b0);
  float lo1 = fminf(a1, b1), hi1 = fmaxf(a1, b1);
  float lo2 = fminf(a2, b2);
  a0 = lo0;
  a1 = fminf(hi0, lo1);
  a2 = fminf(fmaxf(hi0, lo1), fminf(hi1, lo2));
}

__global__ __launch_bounds__(256) void dist_mfma(
    const short* __restrict__ phip, const short* __restrict__ Cpk,
    const float* __restrict__ c2g, float* __restrict__ out) {
  __shared__ __align__(16) short sA[2 * KCD_ * 64 * 8];   // 28 KB: 2 chunks of A-frags
  __shared__ float mb[4][32][3];
  const int wv = threadIdx.x >> 6, ln = threadIdx.x & 63;
  const int chunk0 = blockIdx.x * 2;

  // stage both 16-pixel chunks' A-frags (byte-identical copy of phipack layout)
  for (int item = threadIdx.x; item < 2 * KCD_ * 64; item += 256) {
    int c = item / (KCD_ * 64), off = item - c * (KCD_ * 64);
    *(bh8*)(sA + (size_t)item * 8) =
        *(const bh8*)(phip + (size_t)(chunk0 + c) * PCH_ + (size_t)off * 8);
  }
  __syncthreads();

  // f2 per pixel row (self-consistent with bf16 MFMA dot)
  float f2r[2][4];
#pragma unroll
  for (int rc = 0; rc < 2; ++rc) {
    float sum = 0.f;
#pragma unroll
    for (int kc = 0; kc < KCD_; ++kc) {
      bh8 a = *(const bh8*)(sA + (size_t)(rc * (KCD_ * 64) + kc * 64 + ln) * 8);
#pragma unroll
      for (int j = 0; j < 8; ++j) { float v = bf2f(a[j]); sum = fmaf(v, v, sum); }
    }
    sum += __shfl_xor(sum, 16, 64);
    sum += __shfl_xor(sum, 32, 64);
#pragma unroll
    for (int r = 0; r < 4; ++r) f2r[rc][r] = __shfl(sum, ((ln >> 4) << 2) + r, 64);
  }

  float t3[2][4][3];
#pragma unroll
  for (int rc = 0; rc < 2; ++rc)
#pragma unroll
    for (int r = 0; r < 4; ++r) { t3[rc][r][0] = 1e30f; t3[rc][r][1] = 1e30f; t3[rc][r][2] = 1e30f; }

  // this wave's 49 N-chunks; B-frag shared by both pixel-chunk MFMA chains
  const short* bbase = Cpk + (size_t)(wv * 49) * (KCD_ * 512) + ln * 8;
  for (int i = 0; i < 49; ++i) {
    const short* bp = bbase + (size_t)i * (KCD_ * 512);
    // anti-LICM: opaque per-iteration pointers so the 28 LDS A-frag loads
    // cannot be hoisted out of the i-loop (R5/R6/R7 spill root cause).
    const short* a0p = sA + (size_t)ln * 8;
    const short* a1p = a0p + (size_t)(KCD_ * 64) * 8;
    asm volatile("" : "+v"(a0p), "+v"(a1p));
    f32x4 acc0 = {0.f, 0.f, 0.f, 0.f}, acc1 = {0.f, 0.f, 0.f, 0.f};
#pragma unroll
    for (int kc = 0; kc < KCD_; ++kc) {
      bh8 b  = *(const bh8*)(bp + kc * 512);
      bh8 a0 = *(const bh8*)(a0p + (size_t)kc * 512);
      bh8 a1 = *(const bh8*)(a1p + (size_t)kc * 512);
      acc0 = __builtin_amdgcn_mfma_f32_16x16x32_bf16(a0, b, acc0, 0, 0, 0);
      acc1 = __builtin_amdgcn_mfma_f32_16x16x32_bf16(a1, b, acc1, 0, 0, 0);
    }
    int nc = wv * 49 + i;
    float c2v = c2g[nc * 16 + (ln & 15)];
#pragma unroll
    for (int r = 0; r < 4; ++r) {
      insert3(t3[0][r][0], t3[0][r][1], t3[0][r][2], f2r[0][r] + c2v - 2.0f * acc0[r]);
      insert3(t3[1][r][0], t3[1][r][1], t3[1][r][2], f2r[1][r] + c2v - 2.0f * acc1[r]);
    }
  }

  // merge the 16 column-lanes (same pixel rows, different centers)
#pragma unroll
  for (int m = 1; m <= 8; m <<= 1) {
#pragma unroll
    for (int rc = 0; rc < 2; ++rc)
#pragma unroll
      for (int r = 0; r < 4; ++r) {
        float b0 = __shfl_xor(t3[rc][r][0], m, 64);
        float b1 = __shfl_xor(t3[rc][r][1], m, 64);
        float b2 = __shfl_xor(t3[rc][r][2], m, 64);
        merge3(t3[rc][r][0], t3[rc][r][1], t3[rc][r][2], b0, b1, b2);
      }
  }

  // cross-wave merge (waves hold disjoint center ranges for the same 32 pixels)
  if ((ln & 15) == 0) {
#pragma unroll
    for (int rc = 0; rc < 2; ++rc)
#pragma unroll
      for (int r = 0; r < 4; ++r) {
        int row = rc * 16 + ((ln >> 4) << 2) + r;
        mb[wv][row][0] = t3[rc][r][0];
        mb[wv][row][1] = t3[rc][r][1];
        mb[wv][row][2] = t3[rc][r][2];
      }
  }
  __syncthreads();
  if (threadIdx.x < 32) {
    int row = threadIdx.x;
    float a0 = mb[0][row][0], a1 = mb[0][row][1], a2 = mb[0][row][2];
#pragma unroll
    for (int w2 = 1; w2 < 4; ++w2) merge3(a0, a1, a2, mb[w2][row][0], mb[w2][row][1], mb[w2][row][2]);
    float d0 = sqrtf(fmaxf(a0, 0.f));
    float d1 = sqrtf(fmaxf(a1, 0.f));
    float d2 = sqrtf(fmaxf(a2, 0.f));
    float s0 = 1.0f / (1.0f + expf(d0 - d1) + expf(d0 - d2));
    out[chunk0 * 16 + row] = s0 * d0;
  }
}

// ---------------- launch ----------------
extern "C" void kernel_launch(void* const* d_in, const int* in_sizes, int n_in,
                              void* d_out, int out_size, void* d_ws, size_t ws_size,
                              hipStream_t stream) {
  const float* p0 = (const float*)d_in[0];
  const float* p1 = (const float*)d_in[1];
  const float* p2 = (const float*)d_in[2];
  const float* cw = (const float*)d_in[3];
  const float* cb = (const float*)d_in[4];
  const float* C  = (const float*)d_in[5];
  float* out = (float*)d_out;

  short* desc = (short*)d_ws;
  short* Cpk  = desc + (size_t)25088 * KD_;
  short* Wpk  = Cpk + (size_t)NCHD_ * KCD_ * 512;
  float* c2   = (float*)(Wpk + (size_t)NCHP_ * KCP_ * 512);

  desc0_kernel<<<dim3(4, 56, 8),  256, 0, stream>>>(p0, desc);
  desc1_kernel<<<dim3(8, 56, 8),  256, 0, stream>>>(p1, desc);
  desc2_kernel<<<dim3(16, 56, 8), 256, 0, stream>>>(p2, desc);
  cent2_kernel<<<(NC_ + 255) / 256, 256, 0, stream>>>(C, c2);
  cpack_kernel<<<NCHD_ * KCD_ * 64 / 256, 256, 0, stream>>>(C, Cpk);
  wpack_kernel<<<NCHP_ * KCP_ * 64 / 256, 256, 0, stream>>>(cw, Wpk);
  phi_mfma<<<25088 / 32, 256, 0, stream>>>(desc, Wpk, cw, cb, desc);
  dist_mfma<<<25088 / 32, 256, 0, stream>>>(desc, Cpk, c2, out);
}

// Round 9
// 703.724 us; speedup vs baseline: 1.2514x; 1.1585x over previous
//
#include <hip/hip_runtime.h>
#include <math.h>

// ---------------- problem constants ----------------
#define B_    8
#define H_    56
#define W_    56
#define HW_   3136
#define C0_   256
#define C1_   512
#define C2_   1024
#define DIN_  1794      // raw conv_w K (includes 2 coord cols, folded into epilogue)
#define KD_   1792      // descriptor K (GEMM K), 56 chunks of 32
#define KCP_  56        // phi K-chunks
#define DOUT_ 448
#define NCHP_ 28        // phi N-chunks (448/16)
#define NC_   3136      // centers
#define NCHD_ 196       // dist N-chunks (3136/16)
#define KCD_  14        // dist K-chunks (448/32)
#define DTS_  452       // LDS D-tile row stride (floats)
#define PCH_  28672     // phip chunk stride in shorts (in-place alias of desc pixels)

typedef __attribute__((ext_vector_type(8))) short bh8;
typedef __attribute__((ext_vector_type(4))) float f32x4;

__device__ __forceinline__ short f2bf(float f) {
  union { float f; unsigned u; } v; v.f = f;
  unsigned r = v.u + 0x7fffu + ((v.u >> 16) & 1u);
  return (short)(r >> 16);
}
__device__ __forceinline__ float bf2f(short s) {
  union { unsigned u; float f; } v; v.u = ((unsigned)(unsigned short)s) << 16;
  return v.f;
}

// ======== desc0: pool(p0) -> desc[:, 0:256], transposed, bf16 ========
__global__ __launch_bounds__(256) void desc0_kernel(const float* __restrict__ p0,
                                                    short* __restrict__ desc) {
  __shared__ float sv[64 * 57];
  const int c0 = blockIdx.x * 64, h = blockIdx.y, b = blockIdx.z;
  for (int item = threadIdx.x; item < 64 * 56; item += 256) {
    int x = item % 56, c = item / 56;
    const float* src = p0 + (((size_t)(b * C0_ + c0 + c)) * 56 + h) * 56 + x;
    float s = src[0];
    if (h > 0)  s += src[-56];
    if (h < 55) s += src[56];
    sv[c * 57 + x] = s;
  }
  __syncthreads();
  for (int item = threadIdx.x; item < 56 * 8; item += 256) {
    int g = item & 7, w = item >> 3;
    bh8 o;
#pragma unroll
    for (int j = 0; j < 8; ++j) {
      const float* s0 = sv + (g * 8 + j) * 57;
      float v = s0[w];
      if (w > 0)  v += s0[w - 1];
      if (w < 55) v += s0[w + 1];
      o[j] = f2bf(v * (1.0f / 9.0f));
    }
    size_t pid = (size_t)b * HW_ + h * 56 + w;
    *(bh8*)(desc + pid * KD_ + c0 + g * 8) = o;
  }
}

// ======== desc1: pool(p1)+bilinear x2 -> desc[:, 256:768] ========
__global__ __launch_bounds__(256) void desc1_kernel(const float* __restrict__ p1,
                                                    short* __restrict__ desc) {
  __shared__ float sv[2 * 64 * 29];
  const int c0 = blockIdx.x * 64, h = blockIdx.y, b = blockIdx.z;
  float sy = (h + 0.5f) * 0.5f - 0.5f;
  float fyf = floorf(sy);
  float fy = sy - fyf;
  int iy = (int)fyf;
  int pya = min(max(iy, 0), 27), pyb = min(max(iy + 1, 0), 27);
  for (int item = threadIdx.x; item < 64 * 2 * 28; item += 256) {
    int x = item % 28;
    int pr = (item / 28) & 1;
    int c = item / 56;
    int r = pr ? pyb : pya;
    const float* src = p1 + (((size_t)(b * C1_ + c0 + c)) * 28 + r) * 28 + x;
    float s = src[0];
    if (r > 0)  s += src[-28];
    if (r < 27) s += src[28];
    sv[pr * (64 * 29) + c * 29 + x] = s;
  }
  __syncthreads();
  for (int item = threadIdx.x; item < 56 * 8; item += 256) {
    int g = item & 7, w = item >> 3;
    float sx = (w + 0.5f) * 0.5f - 0.5f;
    float fxf = floorf(sx);
    float fx = sx - fxf;
    int ix = (int)fxf;
    int x0 = min(max(ix, 0), 27), x1 = min(max(ix + 1, 0), 27);
    bh8 o;
#pragma unroll
    for (int j = 0; j < 8; ++j) {
      const float* s0 = sv + (g * 8 + j) * 29;
      const float* s1 = s0 + 64 * 29;
      float p00 = s0[x0] + (x0 > 0 ? s0[x0 - 1] : 0.f) + (x0 < 27 ? s0[x0 + 1] : 0.f);
      float p01 = s0[x1] + (x1 > 0 ? s0[x1 - 1] : 0.f) + (x1 < 27 ? s0[x1 + 1] : 0.f);
      float p10 = s1[x0] + (x0 > 0 ? s1[x0 - 1] : 0.f) + (x0 < 27 ? s1[x0 + 1] : 0.f);
      float p11 = s1[x1] + (x1 > 0 ? s1[x1 - 1] : 0.f) + (x1 < 27 ? s1[x1 + 1] : 0.f);
      float top = p00 + fx * (p01 - p00);
      float bot = p10 + fx * (p11 - p10);
      o[j] = f2bf((top + fy * (bot - top)) * (1.0f / 9.0f));
    }
    size_t pid = (size_t)b * HW_ + h * 56 + w;
    *(bh8*)(desc + pid * KD_ + C0_ + c0 + g * 8) = o;
  }
}

// ======== desc2: pool(p2)+bilinear x4 -> desc[:, 768:1792] ========
__global__ __launch_bounds__(256) void desc2_kernel(const float* __restrict__ p2,
                                                    short* __restrict__ desc) {
  __shared__ float sv[2 * 64 * 15];
  const int c0 = blockIdx.x * 64, h = blockIdx.y, b = blockIdx.z;
  float sy = (h + 0.5f) * 0.25f - 0.5f;
  float fyf = floorf(sy);
  float fy = sy - fyf;
  int iy = (int)fyf;
  int pya = min(max(iy, 0), 13), pyb = min(max(iy + 1, 0), 13);
  for (int item = threadIdx.x; item < 64 * 2 * 14; item += 256) {
    int x = item % 14;
    int pr = (item / 14) & 1;
    int c = item / 28;
    int r = pr ? pyb : pya;
    const float* src = p2 + (((size_t)(b * C2_ + c0 + c)) * 14 + r) * 14 + x;
    float s = src[0];
    if (r > 0)  s += src[-14];
    if (r < 13) s += src[14];
    sv[pr * (64 * 15) + c * 15 + x] = s;
  }
  __syncthreads();
  for (int item = threadIdx.x; item < 56 * 8; item += 256) {
    int g = item & 7, w = item >> 3;
    float sx = (w + 0.5f) * 0.25f - 0.5f;
    float fxf = floorf(sx);
    float fx = sx - fxf;
    int ix = (int)fxf;
    int x0 = min(max(ix, 0), 13), x1 = min(max(ix + 1, 0), 13);
    bh8 o;
#pragma unroll
    for (int j = 0; j < 8; ++j) {
      const float* s0 = sv + (g * 8 + j) * 15;
      const float* s1 = s0 + 64 * 15;
      float p00 = s0[x0] + (x0 > 0 ? s0[x0 - 1] : 0.f) + (x0 < 13 ? s0[x0 + 1] : 0.f);
      float p01 = s0[x1] + (x1 > 0 ? s0[x1 - 1] : 0.f) + (x1 < 13 ? s0[x1 + 1] : 0.f);
      float p10 = s1[x0] + (x0 > 0 ? s1[x0 - 1] : 0.f) + (x0 < 13 ? s1[x0 + 1] : 0.f);
      float p11 = s1[x1] + (x1 > 0 ? s1[x1 - 1] : 0.f) + (x1 < 13 ? s1[x1 + 1] : 0.f);
      float top = p00 + fx * (p01 - p00);
      float bot = p10 + fx * (p11 - p10);
      o[j] = f2bf((top + fy * (bot - top)) * (1.0f / 9.0f));
    }
    size_t pid = (size_t)b * HW_ + h * 56 + w;
    *(bh8*)(desc + pid * KD_ + C0_ + C1_ + c0 + g * 8) = o;
  }
}

// ---------------- |c_j|^2 from bf16-rounded C ----------------
__global__ void cent2_kernel(const float* __restrict__ C, float* __restrict__ c2) {
  int j = blockIdx.x * blockDim.x + threadIdx.x;
  if (j >= NC_) return;
  float s = 0.f;
  for (int d = 0; d < DOUT_; ++d) {
    float v = bf2f(f2bf(C[(size_t)d * NC_ + j]));
    s = fmaf(v, v, s);
  }
  c2[j] = s;
}

// ---------------- pack C (K=448 x N=3136) into B-frag layout ----------------
__global__ void cpack_kernel(const float* __restrict__ C, short* __restrict__ Cpk) {
  int idx = blockIdx.x * 256 + threadIdx.x;       // NCHD_*KCD_*64 = 175616 exact
  int ln = idx & 63;
  int kc = (idx >> 6) % KCD_;
  int nc = idx / (KCD_ * 64);
  int n  = nc * 16 + (ln & 15);
  int k0 = kc * 32 + ((ln >> 4) << 3);
  bh8 o;
#pragma unroll
  for (int j = 0; j < 8; ++j) o[j] = f2bf(C[(size_t)(k0 + j) * NC_ + n]);
  *(bh8*)(Cpk + (size_t)idx * 8) = o;
}

// ---------------- pack W^T (K=1792 x N=448) into B-frag layout ----------------
__global__ void wpack_kernel(const float* __restrict__ W, short* __restrict__ Wpk) {
  int idx = blockIdx.x * 256 + threadIdx.x;       // NCHP_*KCP_*64 = 100352 exact
  int ln = idx & 63;
  int kc = (idx >> 6) % KCP_;
  int nc = idx / (KCP_ * 64);
  int n  = nc * 16 + (ln & 15);
  int k0 = kc * 32 + ((ln >> 4) << 3);
  bh8 o;
#pragma unroll
  for (int j = 0; j < 8; ++j) o[j] = f2bf(W[(size_t)n * DIN_ + k0 + j]);
  *(bh8*)(Wpk + (size_t)idx * 8) = o;
}

// ======== phi: A-frags direct from desc; bias+coords fused; in-place phipack ========
__global__ __launch_bounds__(256) void phi_mfma(
    const short* __restrict__ desc, const short* __restrict__ Wpk,
    const float* __restrict__ cw, const float* __restrict__ cb,
    short* __restrict__ phip /* aliases desc */) {
  __shared__ __align__(16) float Dt[16 * DTS_];   // 28.9 KB
  const int wv = threadIdx.x >> 6, ln = threadIdx.x & 63;
  const int pix0 = blockIdx.x * 32;
  const short* aptr = desc + ((size_t)(pix0 + (ln & 15))) * KD_ + ((ln >> 4) << 3);

  f32x4 acc[2][7];
#pragma unroll
  for (int rc = 0; rc < 2; ++rc)
#pragma unroll
    for (int i = 0; i < 7; ++i) acc[rc][i] = (f32x4){0.f, 0.f, 0.f, 0.f};

  const short* bbase = Wpk + (size_t)(wv * 7) * (KCP_ * 512) + ln * 8;
  for (int kc = 0; kc < KCP_; ++kc) {
    bh8 a0 = *(const bh8*)(aptr + kc * 32);
    bh8 a1 = *(const bh8*)(aptr + 16 * KD_ + kc * 32);
    const short* bp = bbase + kc * 512;
#pragma unroll
    for (int i = 0; i < 7; ++i) {
      bh8 bfr = *(const bh8*)(bp + (size_t)i * (KCP_ * 512));
      acc[0][i] = __builtin_amdgcn_mfma_f32_16x16x32_bf16(a0, bfr, acc[0][i], 0, 0, 0);
      acc[1][i] = __builtin_amdgcn_mfma_f32_16x16x32_bf16(a1, bfr, acc[1][i], 0, 0, 0);
    }
  }

  for (int rc = 0; rc < 2; ++rc) {
    __syncthreads();   // rc=0: all desc reads done; rc=1: all rc=0 repack reads done
#pragma unroll
    for (int i = 0; i < 7; ++i) {
      int col = (wv * 7 + i) * 16 + (ln & 15);
      float bias = cb[col];
      float wx = cw[(size_t)col * DIN_ + 1792];
      float wy = cw[(size_t)col * DIN_ + 1793];
#pragma unroll
      for (int r = 0; r < 4; ++r) {
        int row = ((ln >> 4) << 2) + r;
        int pid = pix0 + rc * 16 + row;
        int hw = pid % HW_;
        int hh = hw / 56, ww = hw % 56;
        float xx = (float)hh * (2.0f / 55.0f) - 1.0f;
        float yy = (float)ww * (2.0f / 55.0f) - 1.0f;
        Dt[row * DTS_ + col] = acc[rc][i][r] + bias + wx * xx + wy * yy;
      }
    }
    __syncthreads();
    short* op = phip + (size_t)(blockIdx.x * 2 + rc) * PCH_;
    for (int item = threadIdx.x; item < KCD_ * 64; item += 256) {
      int kc = item >> 6, lp = item & 63;
      int m = lp & 15, k0 = kc * 32 + ((lp >> 4) << 3);
      bh8 o;
#pragma unroll
      for (int j = 0; j < 8; ++j) o[j] = f2bf(Dt[m * DTS_ + k0 + j]);
      *(bh8*)(op + (size_t)item * 8) = o;
    }
  }
}

// ======== dist v7: exact v2 per-wave body (proven no-spill: no LDS, no barrier);
// each wave does a QUARTER of N (49 chunks) and writes its partial top-3 (d^2)
// to a 1.6 MB global buffer. Grid 1568 x 4 waves = 6272 waves (~24/CU).
__device__ __forceinline__ void insert3(float& t0, float& t1, float& t2, float v) {
  if (v < t2) {
    if (v < t1) {
      t2 = t1;
      if (v < t0) { t1 = t0; t0 = v; } else t1 = v;
    } else t2 = v;
  }
}
__device__ __forceinline__ void merge3(float& a0, float& a1, float& a2,
                                       float b0, float b1, float b2) {
  float lo0 = fminf(a0, b0), hi0 = fmaxf(a0, b0);
  float lo1 = fminf(a1, b1), hi1 = fmaxf(a1, b1);
  float lo2 = fminf(a2, b2);
  a0 = lo0;
  a1 = fminf(hi0, lo1);
  a2 = fminf(fmaxf(hi0, lo1), fminf(hi1, lo2));
}

__global__ __launch_bounds__(256) void dist_part(
    const short* __restrict__ phip, const short* __restrict__ Cpk,
    const float* __restrict__ c2g, float* __restrict__ part) {
  const int wv = threadIdx.x >> 6, ln = threadIdx.x & 63;
  const int chunk = blockIdx.x;   // one 16-pixel chunk per block, 1568 total

  bh8 A[KCD_];
  const short* ap = phip + (size_t)chunk * PCH_ + ln * 8;
#pragma unroll
  for (int kc = 0; kc < KCD_; ++kc) A[kc] = *(const bh8*)(ap + kc * 512);

  // f2 per pixel row (self-consistent with bf16 MFMA dot)
  float sum = 0.f;
#pragma unroll
  for (int kc = 0; kc < KCD_; ++kc)
#pragma unroll
    for (int j = 0; j < 8; ++j) { float v = bf2f(A[kc][j]); sum = fmaf(v, v, sum); }
  sum += __shfl_xor(sum, 16, 64);
  sum += __shfl_xor(sum, 32, 64);
  float f2r[4];
#pragma unroll
  for (int r = 0; r < 4; ++r) f2r[r] = __shfl(sum, ((ln >> 4) << 2) + r, 64);

  float t3[4][3];
#pragma unroll
  for (int r = 0; r < 4; ++r) { t3[r][0] = 1e30f; t3[r][1] = 1e30f; t3[r][2] = 1e30f; }

  // this wave's quarter of the N-chunks
  const short* bbase = Cpk + (size_t)(wv * 49) * (KCD_ * 512) + ln * 8;
  for (int i = 0; i < 49; ++i) {
    const short* bp = bbase + (size_t)i * (KCD_ * 512);
    f32x4 acc = {0.f, 0.f, 0.f, 0.f};
#pragma unroll
    for (int kc = 0; kc < KCD_; ++kc) {
      bh8 b = *(const bh8*)(bp + kc * 512);
      acc = __builtin_amdgcn_mfma_f32_16x16x32_bf16(A[kc], b, acc, 0, 0, 0);
    }
    int nc = wv * 49 + i;
    float c2v = c2g[nc * 16 + (ln & 15)];
#pragma unroll
    for (int r = 0; r < 4; ++r)
      insert3(t3[r][0], t3[r][1], t3[r][2], f2r[r] + c2v - 2.0f * acc[r]);
  }

  // merge the 16 column-lanes (same pixel rows, different centers) — shfl only
#pragma unroll
  for (int m = 1; m <= 8; m <<= 1) {
#pragma unroll
    for (int r = 0; r < 4; ++r) {
      float b0 = __shfl_xor(t3[r][0], m, 64);
      float b1 = __shfl_xor(t3[r][1], m, 64);
      float b2 = __shfl_xor(t3[r][2], m, 64);
      merge3(t3[r][0], t3[r][1], t3[r][2], b0, b1, b2);
    }
  }

  if ((ln & 15) == 0) {
#pragma unroll
    for (int r = 0; r < 4; ++r) {
      int row = ((ln >> 4) << 2) + r;
      float* q = part + ((size_t)(chunk * 16 + row)) * 16 + wv * 4;
      q[0] = t3[r][0];
      q[1] = t3[r][1];
      q[2] = t3[r][2];
    }
  }
}

// ======== merge: combine 4 partial triples per pixel, softmin score ========
__global__ __launch_bounds__(256) void merge_kernel(const float* __restrict__ part,
                                                    float* __restrict__ out) {
  int p = blockIdx.x * 256 + threadIdx.x;   // 25088 exact
  const float* q = part + (size_t)p * 16;
  float a0 = q[0], a1 = q[1], a2 = q[2];
#pragma unroll
  for (int w = 1; w < 4; ++w) merge3(a0, a1, a2, q[w * 4], q[w * 4 + 1], q[w * 4 + 2]);
  float d0 = sqrtf(fmaxf(a0, 0.f));
  float d1 = sqrtf(fmaxf(a1, 0.f));
  float d2 = sqrtf(fmaxf(a2, 0.f));
  float s0 = 1.0f / (1.0f + expf(d0 - d1) + expf(d0 - d2));
  out[p] = s0 * d0;
}

// ---------------- launch ----------------
extern "C" void kernel_launch(void* const* d_in, const int* in_sizes, int n_in,
                              void* d_out, int out_size, void* d_ws, size_t ws_size,
                              hipStream_t stream) {
  const float* p0 = (const float*)d_in[0];
  const float* p1 = (const float*)d_in[1];
  const float* p2 = (const float*)d_in[2];
  const float* cw = (const float*)d_in[3];
  const float* cb = (const float*)d_in[4];
  const float* C  = (const float*)d_in[5];
  float* out = (float*)d_out;

  short* desc = (short*)d_ws;                                   // 44,957,696 shorts
  short* Cpk  = desc + (size_t)25088 * KD_;                     //  1,404,928 shorts
  short* Wpk  = Cpk + (size_t)NCHD_ * KCD_ * 512;               //    802,816 shorts
  float* c2   = (float*)(Wpk + (size_t)NCHP_ * KCP_ * 512);     //      3,136 floats
  float* part = c2 + NC_;                                       //    401,408 floats (~1.6 MB)

  desc0_kernel<<<dim3(4, 56, 8),  256, 0, stream>>>(p0, desc);
  desc1_kernel<<<dim3(8, 56, 8),  256, 0, stream>>>(p1, desc);
  desc2_kernel<<<dim3(16, 56, 8), 256, 0, stream>>>(p2, desc);
  cent2_kernel<<<(NC_ + 255) / 256, 256, 0, stream>>>(C, c2);
  cpack_kernel<<<NCHD_ * KCD_ * 64 / 256, 256, 0, stream>>>(C, Cpk);
  wpack_kernel<<<NCHP_ * KCP_ * 64 / 256, 256, 0, stream>>>(cw, Wpk);
  phi_mfma<<<25088 / 32, 256, 0, stream>>>(desc, Wpk, cw, cb, desc);
  dist_part<<<25088 / 16, 256, 0, stream>>>(desc, Cpk, c2, part);
  merge_kernel<<<25088 / 256, 256, 0, stream>>>(part, out);
}

// Round 10
// 699.628 us; speedup vs baseline: 1.2587x; 1.0059x over previous
//
#include <hip/hip_runtime.h>
#include <math.h>

// ---------------- problem constants ----------------
#define B_    8
#define H_    56
#define W_    56
#define HW_   3136
#define C0_   256
#define C1_   512
#define C2_   1024
#define DIN_  1794      // raw conv_w K (includes 2 coord cols, folded into epilogue)
#define KD_   1792      // descriptor K (GEMM K), 56 chunks of 32
#define KCP_  56        // phi K-chunks
#define DOUT_ 448
#define NCHP_ 28        // phi N-chunks (448/16)
#define NC_   3136      // centers
#define NCHD_ 196       // dist N-chunks (3136/16)
#define KCD_  14        // dist K-chunks (448/32)
#define DTS_  452       // LDS D-tile row stride (floats)
#define PCH_  28672     // phip chunk stride in shorts (in-place alias of desc pixels)

typedef __attribute__((ext_vector_type(8))) short bh8;
typedef __attribute__((ext_vector_type(4))) float f32x4;

__device__ __forceinline__ short f2bf(float f) {
  union { float f; unsigned u; } v; v.f = f;
  unsigned r = v.u + 0x7fffu + ((v.u >> 16) & 1u);
  return (short)(r >> 16);
}
__device__ __forceinline__ float bf2f(short s) {
  union { unsigned u; float f; } v; v.u = ((unsigned)(unsigned short)s) << 16;
  return v.f;
}

// ======== desc0: pool(p0) -> desc[:, 0:256], transposed, bf16 ========
__global__ __launch_bounds__(256) void desc0_kernel(const float* __restrict__ p0,
                                                    short* __restrict__ desc) {
  __shared__ float sv[64 * 57];
  const int c0 = blockIdx.x * 64, h = blockIdx.y, b = blockIdx.z;
  for (int item = threadIdx.x; item < 64 * 56; item += 256) {
    int x = item % 56, c = item / 56;
    const float* src = p0 + (((size_t)(b * C0_ + c0 + c)) * 56 + h) * 56 + x;
    float s = src[0];
    if (h > 0)  s += src[-56];
    if (h < 55) s += src[56];
    sv[c * 57 + x] = s;
  }
  __syncthreads();
  for (int item = threadIdx.x; item < 56 * 8; item += 256) {
    int g = item & 7, w = item >> 3;
    bh8 o;
#pragma unroll
    for (int j = 0; j < 8; ++j) {
      const float* s0 = sv + (g * 8 + j) * 57;
      float v = s0[w];
      if (w > 0)  v += s0[w - 1];
      if (w < 55) v += s0[w + 1];
      o[j] = f2bf(v * (1.0f / 9.0f));
    }
    size_t pid = (size_t)b * HW_ + h * 56 + w;
    *(bh8*)(desc + pid * KD_ + c0 + g * 8) = o;
  }
}

// ======== desc1: pool(p1)+bilinear x2 -> desc[:, 256:768] ========
__global__ __launch_bounds__(256) void desc1_kernel(const float* __restrict__ p1,
                                                    short* __restrict__ desc) {
  __shared__ float sv[2 * 64 * 29];
  const int c0 = blockIdx.x * 64, h = blockIdx.y, b = blockIdx.z;
  float sy = (h + 0.5f) * 0.5f - 0.5f;
  float fyf = floorf(sy);
  float fy = sy - fyf;
  int iy = (int)fyf;
  int pya = min(max(iy, 0), 27), pyb = min(max(iy + 1, 0), 27);
  for (int item = threadIdx.x; item < 64 * 2 * 28; item += 256) {
    int x = item % 28;
    int pr = (item / 28) & 1;
    int c = item / 56;
    int r = pr ? pyb : pya;
    const float* src = p1 + (((size_t)(b * C1_ + c0 + c)) * 28 + r) * 28 + x;
    float s = src[0];
    if (r > 0)  s += src[-28];
    if (r < 27) s += src[28];
    sv[pr * (64 * 29) + c * 29 + x] = s;
  }
  __syncthreads();
  for (int item = threadIdx.x; item < 56 * 8; item += 256) {
    int g = item & 7, w = item >> 3;
    float sx = (w + 0.5f) * 0.5f - 0.5f;
    float fxf = floorf(sx);
    float fx = sx - fxf;
    int ix = (int)fxf;
    int x0 = min(max(ix, 0), 27), x1 = min(max(ix + 1, 0), 27);
    bh8 o;
#pragma unroll
    for (int j = 0; j < 8; ++j) {
      const float* s0 = sv + (g * 8 + j) * 29;
      const float* s1 = s0 + 64 * 29;
      float p00 = s0[x0] + (x0 > 0 ? s0[x0 - 1] : 0.f) + (x0 < 27 ? s0[x0 + 1] : 0.f);
      float p01 = s0[x1] + (x1 > 0 ? s0[x1 - 1] : 0.f) + (x1 < 27 ? s0[x1 + 1] : 0.f);
      float p10 = s1[x0] + (x0 > 0 ? s1[x0 - 1] : 0.f) + (x0 < 27 ? s1[x0 + 1] : 0.f);
      float p11 = s1[x1] + (x1 > 0 ? s1[x1 - 1] : 0.f) + (x1 < 27 ? s1[x1 + 1] : 0.f);
      float top = p00 + fx * (p01 - p00);
      float bot = p10 + fx * (p11 - p10);
      o[j] = f2bf((top + fy * (bot - top)) * (1.0f / 9.0f));
    }
    size_t pid = (size_t)b * HW_ + h * 56 + w;
    *(bh8*)(desc + pid * KD_ + C0_ + c0 + g * 8) = o;
  }
}

// ======== desc2: pool(p2)+bilinear x4 -> desc[:, 768:1792] ========
__global__ __launch_bounds__(256) void desc2_kernel(const float* __restrict__ p2,
                                                    short* __restrict__ desc) {
  __shared__ float sv[2 * 64 * 15];
  const int c0 = blockIdx.x * 64, h = blockIdx.y, b = blockIdx.z;
  float sy = (h + 0.5f) * 0.25f - 0.5f;
  float fyf = floorf(sy);
  float fy = sy - fyf;
  int iy = (int)fyf;
  int pya = min(max(iy, 0), 13), pyb = min(max(iy + 1, 0), 13);
  for (int item = threadIdx.x; item < 64 * 2 * 14; item += 256) {
    int x = item % 14;
    int pr = (item / 14) & 1;
    int c = item / 28;
    int r = pr ? pyb : pya;
    const float* src = p2 + (((size_t)(b * C2_ + c0 + c)) * 14 + r) * 14 + x;
    float s = src[0];
    if (r > 0)  s += src[-14];
    if (r < 13) s += src[14];
    sv[pr * (64 * 15) + c * 15 + x] = s;
  }
  __syncthreads();
  for (int item = threadIdx.x; item < 56 * 8; item += 256) {
    int g = item & 7, w = item >> 3;
    float sx = (w + 0.5f) * 0.25f - 0.5f;
    float fxf = floorf(sx);
    float fx = sx - fxf;
    int ix = (int)fxf;
    int x0 = min(max(ix, 0), 13), x1 = min(max(ix + 1, 0), 13);
    bh8 o;
#pragma unroll
    for (int j = 0; j < 8; ++j) {
      const float* s0 = sv + (g * 8 + j) * 15;
      const float* s1 = s0 + 64 * 15;
      float p00 = s0[x0] + (x0 > 0 ? s0[x0 - 1] : 0.f) + (x0 < 13 ? s0[x0 + 1] : 0.f);
      float p01 = s0[x1] + (x1 > 0 ? s0[x1 - 1] : 0.f) + (x1 < 13 ? s0[x1 + 1] : 0.f);
      float p10 = s1[x0] + (x0 > 0 ? s1[x0 - 1] : 0.f) + (x0 < 13 ? s1[x0 + 1] : 0.f);
      float p11 = s1[x1] + (x1 > 0 ? s1[x1 - 1] : 0.f) + (x1 < 13 ? s1[x1 + 1] : 0.f);
      float top = p00 + fx * (p01 - p00);
      float bot = p10 + fx * (p11 - p10);
      o[j] = f2bf((top + fy * (bot - top)) * (1.0f / 9.0f));
    }
    size_t pid = (size_t)b * HW_ + h * 56 + w;
    *(bh8*)(desc + pid * KD_ + C0_ + C1_ + c0 + g * 8) = o;
  }
}

// ---------------- |c_j|^2 from bf16-rounded C ----------------
__global__ void cent2_kernel(const float* __restrict__ C, float* __restrict__ c2) {
  int j = blockIdx.x * blockDim.x + threadIdx.x;
  if (j >= NC_) return;
  float s = 0.f;
  for (int d = 0; d < DOUT_; ++d) {
    float v = bf2f(f2bf(C[(size_t)d * NC_ + j]));
    s = fmaf(v, v, s);
  }
  c2[j] = s;
}

// ---------------- pack C (K=448 x N=3136) into B-frag layout ----------------
__global__ void cpack_kernel(const float* __restrict__ C, short* __restrict__ Cpk) {
  int idx = blockIdx.x * 256 + threadIdx.x;       // NCHD_*KCD_*64 = 175616 exact
  int ln = idx & 63;
  int kc = (idx >> 6) % KCD_;
  int nc = idx / (KCD_ * 64);
  int n  = nc * 16 + (ln & 15);
  int k0 = kc * 32 + ((ln >> 4) << 3);
  bh8 o;
#pragma unroll
  for (int j = 0; j < 8; ++j) o[j] = f2bf(C[(size_t)(k0 + j) * NC_ + n]);
  *(bh8*)(Cpk + (size_t)idx * 8) = o;
}

// ---------------- pack W^T (K=1792 x N=448) into B-frag layout ----------------
__global__ void wpack_kernel(const float* __restrict__ W, short* __restrict__ Wpk) {
  int idx = blockIdx.x * 256 + threadIdx.x;       // NCHP_*KCP_*64 = 100352 exact
  int ln = idx & 63;
  int kc = (idx >> 6) % KCP_;
  int nc = idx / (KCP_ * 64);
  int n  = nc * 16 + (ln & 15);
  int k0 = kc * 32 + ((ln >> 4) << 3);
  bh8 o;
#pragma unroll
  for (int j = 0; j < 8; ++j) o[j] = f2bf(W[(size_t)n * DIN_ + k0 + j]);
  *(bh8*)(Wpk + (size_t)idx * 8) = o;
}

// ======== phi: A-frags direct from desc; bias+coords fused; in-place phipack ========
__global__ __launch_bounds__(256) void phi_mfma(
    const short* __restrict__ desc, const short* __restrict__ Wpk,
    const float* __restrict__ cw, const float* __restrict__ cb,
    short* __restrict__ phip /* aliases desc */) {
  __shared__ __align__(16) float Dt[16 * DTS_];   // 28.9 KB
  const int wv = threadIdx.x >> 6, ln = threadIdx.x & 63;
  const int pix0 = blockIdx.x * 32;
  const short* aptr = desc + ((size_t)(pix0 + (ln & 15))) * KD_ + ((ln >> 4) << 3);

  f32x4 acc[2][7];
#pragma unroll
  for (int rc = 0; rc < 2; ++rc)
#pragma unroll
    for (int i = 0; i < 7; ++i) acc[rc][i] = (f32x4){0.f, 0.f, 0.f, 0.f};

  const short* bbase = Wpk + (size_t)(wv * 7) * (KCP_ * 512) + ln * 8;
  for (int kc = 0; kc < KCP_; ++kc) {
    bh8 a0 = *(const bh8*)(aptr + kc * 32);
    bh8 a1 = *(const bh8*)(aptr + 16 * KD_ + kc * 32);
    const short* bp = bbase + kc * 512;
#pragma unroll
    for (int i = 0; i < 7; ++i) {
      bh8 bfr = *(const bh8*)(bp + (size_t)i * (KCP_ * 512));
      acc[0][i] = __builtin_amdgcn_mfma_f32_16x16x32_bf16(a0, bfr, acc[0][i], 0, 0, 0);
      acc[1][i] = __builtin_amdgcn_mfma_f32_16x16x32_bf16(a1, bfr, acc[1][i], 0, 0, 0);
    }
  }

  for (int rc = 0; rc < 2; ++rc) {
    __syncthreads();   // rc=0: all desc reads done; rc=1: all rc=0 repack reads done
#pragma unroll
    for (int i = 0; i < 7; ++i) {
      int col = (wv * 7 + i) * 16 + (ln & 15);
      float bias = cb[col];
      float wx = cw[(size_t)col * DIN_ + 1792];
      float wy = cw[(size_t)col * DIN_ + 1793];
#pragma unroll
      for (int r = 0; r < 4; ++r) {
        int row = ((ln >> 4) << 2) + r;
        int pid = pix0 + rc * 16 + row;
        int hw = pid % HW_;
        int hh = hw / 56, ww = hw % 56;
        float xx = (float)hh * (2.0f / 55.0f) - 1.0f;
        float yy = (float)ww * (2.0f / 55.0f) - 1.0f;
        Dt[row * DTS_ + col] = acc[rc][i][r] + bias + wx * xx + wy * yy;
      }
    }
    __syncthreads();
    short* op = phip + (size_t)(blockIdx.x * 2 + rc) * PCH_;
    for (int item = threadIdx.x; item < KCD_ * 64; item += 256) {
      int kc = item >> 6, lp = item & 63;
      int m = lp & 15, k0 = kc * 32 + ((lp >> 4) << 3);
      bh8 o;
#pragma unroll
      for (int j = 0; j < 8; ++j) o[j] = f2bf(Dt[m * DTS_ + k0 + j]);
      *(bh8*)(op + (size_t)item * 8) = o;
    }
  }
}

// ======== dist v8: exact clone of R4-v2's clean loop body (A[14] + paired
// B-streams + 2 acc chains, no LDS, no barrier). Work mapping only changed:
// each wave covers HALF of N (49 paired iterations). 784 blocks x 4 waves:
// waves 0,1 -> pixel chunk 2b (N-halves 0,1); waves 2,3 -> chunk 2b+1.
__device__ __forceinline__ void insert3(float& t0, float& t1, float& t2, float v) {
  if (v < t2) {
    if (v < t1) {
      t2 = t1;
      if (v < t0) { t1 = t0; t0 = v; } else t1 = v;
    } else t2 = v;
  }
}
__device__ __forceinline__ void merge3(float& a0, float& a1, float& a2,
                                       float b0, float b1, float b2) {
  float lo0 = fminf(a0, b0), hi0 = fmaxf(a0, b0);
  float lo1 = fminf(a1, b1), hi1 = fmaxf(a1, b1);
  float lo2 = fminf(a2, b2);
  a0 = lo0;
  a1 = fminf(hi0, lo1);
  a2 = fminf(fmaxf(hi0, lo1), fminf(hi1, lo2));
}

__global__ __launch_bounds__(256) void dist_part(
    const short* __restrict__ phip, const short* __restrict__ Cpk,
    const float* __restrict__ c2g, float* __restrict__ part) {
  const int wv = threadIdx.x >> 6, ln = threadIdx.x & 63;
  const int chunk = blockIdx.x * 2 + (wv >> 1);   // 16-pixel chunk
  const int half  = wv & 1;                       // which half of the center bank

  bh8 A[KCD_];
  const short* ap = phip + (size_t)chunk * PCH_ + ln * 8;
#pragma unroll
  for (int kc = 0; kc < KCD_; ++kc) A[kc] = *(const bh8*)(ap + kc * 512);

  // f2 per pixel row (self-consistent with bf16 MFMA dot)
  float sum = 0.f;
#pragma unroll
  for (int kc = 0; kc < KCD_; ++kc)
#pragma unroll
    for (int j = 0; j < 8; ++j) { float v = bf2f(A[kc][j]); sum = fmaf(v, v, sum); }
  sum += __shfl_xor(sum, 16, 64);
  sum += __shfl_xor(sum, 32, 64);
  float f2r[4];
#pragma unroll
  for (int r = 0; r < 4; ++r) f2r[r] = __shfl(sum, ((ln >> 4) << 2) + r, 64);

  float t3[4][3];
#pragma unroll
  for (int r = 0; r < 4; ++r) { t3[r][0] = 1e30f; t3[r][1] = 1e30f; t3[r][2] = 1e30f; }

  // this wave's half of the N-chunks, walked in ncA/ncB pairs (v2's body)
  const int nc0 = half * (NCHD_ / 2);
  const short* bbase = Cpk + (size_t)nc0 * (KCD_ * 512) + ln * 8;
  for (int i = 0; i < NCHD_ / 4; ++i) {
    int ncA = i * 2, ncB = i * 2 + 1;
    const short* bpA = bbase + (size_t)ncA * (KCD_ * 512);
    const short* bpB = bbase + (size_t)ncB * (KCD_ * 512);
    f32x4 accA = {0.f, 0.f, 0.f, 0.f}, accB = {0.f, 0.f, 0.f, 0.f};
#pragma unroll
    for (int kc = 0; kc < KCD_; ++kc) {
      bh8 bA = *(const bh8*)(bpA + kc * 512);
      bh8 bB = *(const bh8*)(bpB + kc * 512);
      accA = __builtin_amdgcn_mfma_f32_16x16x32_bf16(A[kc], bA, accA, 0, 0, 0);
      accB = __builtin_amdgcn_mfma_f32_16x16x32_bf16(A[kc], bB, accB, 0, 0, 0);
    }
    float c2A = c2g[(nc0 + ncA) * 16 + (ln & 15)];
    float c2B = c2g[(nc0 + ncB) * 16 + (ln & 15)];
#pragma unroll
    for (int r = 0; r < 4; ++r) {
      insert3(t3[r][0], t3[r][1], t3[r][2], f2r[r] + c2A - 2.0f * accA[r]);
      insert3(t3[r][0], t3[r][1], t3[r][2], f2r[r] + c2B - 2.0f * accB[r]);
    }
  }

  // merge the 16 column-lanes (same pixel rows, different centers) — shfl only
#pragma unroll
  for (int m = 1; m <= 8; m <<= 1) {
#pragma unroll
    for (int r = 0; r < 4; ++r) {
      float b0 = __shfl_xor(t3[r][0], m, 64);
      float b1 = __shfl_xor(t3[r][1], m, 64);
      float b2 = __shfl_xor(t3[r][2], m, 64);
      merge3(t3[r][0], t3[r][1], t3[r][2], b0, b1, b2);
    }
  }

  if ((ln & 15) == 0) {
#pragma unroll
    for (int r = 0; r < 4; ++r) {
      int row = ((ln >> 4) << 2) + r;
      float* q = part + ((size_t)(chunk * 16 + row)) * 8 + half * 4;
      q[0] = t3[r][0];
      q[1] = t3[r][1];
      q[2] = t3[r][2];
    }
  }
}

// ======== merge: combine 2 partial triples per pixel, softmin score ========
__global__ __launch_bounds__(256) void merge_kernel(const float* __restrict__ part,
                                                    float* __restrict__ out) {
  int p = blockIdx.x * 256 + threadIdx.x;   // 25088 exact
  const float* q = part + (size_t)p * 8;
  float a0 = q[0], a1 = q[1], a2 = q[2];
  merge3(a0, a1, a2, q[4], q[5], q[6]);
  float d0 = sqrtf(fmaxf(a0, 0.f));
  float d1 = sqrtf(fmaxf(a1, 0.f));
  float d2 = sqrtf(fmaxf(a2, 0.f));
  float s0 = 1.0f / (1.0f + expf(d0 - d1) + expf(d0 - d2));
  out[p] = s0 * d0;
}

// ---------------- launch ----------------
extern "C" void kernel_launch(void* const* d_in, const int* in_sizes, int n_in,
                              void* d_out, int out_size, void* d_ws, size_t ws_size,
                              hipStream_t stream) {
  const float* p0 = (const float*)d_in[0];
  const float* p1 = (const float*)d_in[1];
  const float* p2 = (const float*)d_in[2];
  const float* cw = (const float*)d_in[3];
  const float* cb = (const float*)d_in[4];
  const float* C  = (const float*)d_in[5];
  float* out = (float*)d_out;

  short* desc = (short*)d_ws;                                   // 44,957,696 shorts
  short* Cpk  = desc + (size_t)25088 * KD_;                     //  1,404,928 shorts
  short* Wpk  = Cpk + (size_t)NCHD_ * KCD_ * 512;               //    802,816 shorts
  float* c2   = (float*)(Wpk + (size_t)NCHP_ * KCP_ * 512);     //      3,136 floats
  float* part = c2 + NC_;                                       //    200,704 floats (~0.8 MB)

  desc0_kernel<<<dim3(4, 56, 8),  256, 0, stream>>>(p0, desc);
  desc1_kernel<<<dim3(8, 56, 8),  256, 0, stream>>>(p1, desc);
  desc2_kernel<<<dim3(16, 56, 8), 256, 0, stream>>>(p2, desc);
  cent2_kernel<<<(NC_ + 255) / 256, 256, 0, stream>>>(C, c2);
  cpack_kernel<<<NCHD_ * KCD_ * 64 / 256, 256, 0, stream>>>(C, Cpk);
  wpack_kernel<<<NCHP_ * KCP_ * 64 / 256, 256, 0, stream>>>(cw, Wpk);
  phi_mfma<<<25088 / 32, 256, 0, stream>>>(desc, Wpk, cw, cb, desc);
  dist_part<<<25088 / 32, 256, 0, stream>>>(desc, Cpk, c2, part);
  merge_kernel<<<25088 / 256, 256, 0, stream>>>(part, out);
}

// Round 11
// 680.748 us; speedup vs baseline: 1.2936x; 1.0277x over previous
//
#include <hip/hip_runtime.h>
#include <math.h>

// ---------------- problem constants ----------------
#define B_    8
#define H_    56
#define W_    56
#define HW_   3136
#define C0_   256
#define C1_   512
#define C2_   1024
#define DIN_  1794      // raw conv_w K (includes 2 coord cols, folded into epilogue)
#define KD_   1792      // descriptor K (GEMM K), 56 chunks of 32
#define KCP_  56        // phi K-chunks
#define DOUT_ 448
#define NCHP_ 28        // phi N-chunks (448/16)
#define NC_   3136      // centers
#define NCHD_ 196       // dist N-chunks (3136/16)
#define KCD_  14        // dist K-chunks (448/32)
#define DTS_  452       // LDS D-tile row stride (floats)
#define PCH_  28672     // phip chunk stride in shorts (in-place alias of desc pixels)

typedef __attribute__((ext_vector_type(8))) short bh8;
typedef __attribute__((ext_vector_type(4))) float f32x4;

__device__ __forceinline__ short f2bf(float f) {
  union { float f; unsigned u; } v; v.f = f;
  unsigned r = v.u + 0x7fffu + ((v.u >> 16) & 1u);
  return (short)(r >> 16);
}
__device__ __forceinline__ float bf2f(short s) {
  union { unsigned u; float f; } v; v.u = ((unsigned)(unsigned short)s) << 16;
  return v.f;
}

// ======== desc0: pool(p0) -> desc[:, 0:256], transposed, bf16 ========
__global__ __launch_bounds__(256) void desc0_kernel(const float* __restrict__ p0,
                                                    short* __restrict__ desc) {
  __shared__ float sv[64 * 57];
  const int c0 = blockIdx.x * 64, h = blockIdx.y, b = blockIdx.z;
  for (int item = threadIdx.x; item < 64 * 56; item += 256) {
    int x = item % 56, c = item / 56;
    const float* src = p0 + (((size_t)(b * C0_ + c0 + c)) * 56 + h) * 56 + x;
    float s = src[0];
    if (h > 0)  s += src[-56];
    if (h < 55) s += src[56];
    sv[c * 57 + x] = s;
  }
  __syncthreads();
  for (int item = threadIdx.x; item < 56 * 8; item += 256) {
    int g = item & 7, w = item >> 3;
    bh8 o;
#pragma unroll
    for (int j = 0; j < 8; ++j) {
      const float* s0 = sv + (g * 8 + j) * 57;
      float v = s0[w];
      if (w > 0)  v += s0[w - 1];
      if (w < 55) v += s0[w + 1];
      o[j] = f2bf(v * (1.0f / 9.0f));
    }
    size_t pid = (size_t)b * HW_ + h * 56 + w;
    *(bh8*)(desc + pid * KD_ + c0 + g * 8) = o;
  }
}

// ======== desc1: pool(p1)+bilinear x2 -> desc[:, 256:768] ========
__global__ __launch_bounds__(256) void desc1_kernel(const float* __restrict__ p1,
                                                    short* __restrict__ desc) {
  __shared__ float sv[2 * 64 * 29];
  const int c0 = blockIdx.x * 64, h = blockIdx.y, b = blockIdx.z;
  float sy = (h + 0.5f) * 0.5f - 0.5f;
  float fyf = floorf(sy);
  float fy = sy - fyf;
  int iy = (int)fyf;
  int pya = min(max(iy, 0), 27), pyb = min(max(iy + 1, 0), 27);
  for (int item = threadIdx.x; item < 64 * 2 * 28; item += 256) {
    int x = item % 28;
    int pr = (item / 28) & 1;
    int c = item / 56;
    int r = pr ? pyb : pya;
    const float* src = p1 + (((size_t)(b * C1_ + c0 + c)) * 28 + r) * 28 + x;
    float s = src[0];
    if (r > 0)  s += src[-28];
    if (r < 27) s += src[28];
    sv[pr * (64 * 29) + c * 29 + x] = s;
  }
  __syncthreads();
  for (int item = threadIdx.x; item < 56 * 8; item += 256) {
    int g = item & 7, w = item >> 3;
    float sx = (w + 0.5f) * 0.5f - 0.5f;
    float fxf = floorf(sx);
    float fx = sx - fxf;
    int ix = (int)fxf;
    int x0 = min(max(ix, 0), 27), x1 = min(max(ix + 1, 0), 27);
    bh8 o;
#pragma unroll
    for (int j = 0; j < 8; ++j) {
      const float* s0 = sv + (g * 8 + j) * 29;
      const float* s1 = s0 + 64 * 29;
      float p00 = s0[x0] + (x0 > 0 ? s0[x0 - 1] : 0.f) + (x0 < 27 ? s0[x0 + 1] : 0.f);
      float p01 = s0[x1] + (x1 > 0 ? s0[x1 - 1] : 0.f) + (x1 < 27 ? s0[x1 + 1] : 0.f);
      float p10 = s1[x0] + (x0 > 0 ? s1[x0 - 1] : 0.f) + (x0 < 27 ? s1[x0 + 1] : 0.f);
      float p11 = s1[x1] + (x1 > 0 ? s1[x1 - 1] : 0.f) + (x1 < 27 ? s1[x1 + 1] : 0.f);
      float top = p00 + fx * (p01 - p00);
      float bot = p10 + fx * (p11 - p10);
      o[j] = f2bf((top + fy * (bot - top)) * (1.0f / 9.0f));
    }
    size_t pid = (size_t)b * HW_ + h * 56 + w;
    *(bh8*)(desc + pid * KD_ + C0_ + c0 + g * 8) = o;
  }
}

// ======== desc2: pool(p2)+bilinear x4 -> desc[:, 768:1792] ========
__global__ __launch_bounds__(256) void desc2_kernel(const float* __restrict__ p2,
                                                    short* __restrict__ desc) {
  __shared__ float sv[2 * 64 * 15];
  const int c0 = blockIdx.x * 64, h = blockIdx.y, b = blockIdx.z;
  float sy = (h + 0.5f) * 0.25f - 0.5f;
  float fyf = floorf(sy);
  float fy = sy - fyf;
  int iy = (int)fyf;
  int pya = min(max(iy, 0), 13), pyb = min(max(iy + 1, 0), 13);
  for (int item = threadIdx.x; item < 64 * 2 * 14; item += 256) {
    int x = item % 14;
    int pr = (item / 14) & 1;
    int c = item / 28;
    int r = pr ? pyb : pya;
    const float* src = p2 + (((size_t)(b * C2_ + c0 + c)) * 14 + r) * 14 + x;
    float s = src[0];
    if (r > 0)  s += src[-14];
    if (r < 13) s += src[14];
    sv[pr * (64 * 15) + c * 15 + x] = s;
  }
  __syncthreads();
  for (int item = threadIdx.x; item < 56 * 8; item += 256) {
    int g = item & 7, w = item >> 3;
    float sx = (w + 0.5f) * 0.25f - 0.5f;
    float fxf = floorf(sx);
    float fx = sx - fxf;
    int ix = (int)fxf;
    int x0 = min(max(ix, 0), 13), x1 = min(max(ix + 1, 0), 13);
    bh8 o;
#pragma unroll
    for (int j = 0; j < 8; ++j) {
      const float* s0 = sv + (g * 8 + j) * 15;
      const float* s1 = s0 + 64 * 15;
      float p00 = s0[x0] + (x0 > 0 ? s0[x0 - 1] : 0.f) + (x0 < 13 ? s0[x0 + 1] : 0.f);
      float p01 = s0[x1] + (x1 > 0 ? s0[x1 - 1] : 0.f) + (x1 < 13 ? s0[x1 + 1] : 0.f);
      float p10 = s1[x0] + (x0 > 0 ? s1[x0 - 1] : 0.f) + (x0 < 13 ? s1[x0 + 1] : 0.f);
      float p11 = s1[x1] + (x1 > 0 ? s1[x1 - 1] : 0.f) + (x1 < 13 ? s1[x1 + 1] : 0.f);
      float top = p00 + fx * (p01 - p00);
      float bot = p10 + fx * (p11 - p10);
      o[j] = f2bf((top + fy * (bot - top)) * (1.0f / 9.0f));
    }
    size_t pid = (size_t)b * HW_ + h * 56 + w;
    *(bh8*)(desc + pid * KD_ + C0_ + C1_ + c0 + g * 8) = o;
  }
}

// ---------------- |c_j|^2 from bf16-rounded C ----------------
__global__ void cent2_kernel(const float* __restrict__ C, float* __restrict__ c2) {
  int j = blockIdx.x * blockDim.x + threadIdx.x;
  if (j >= NC_) return;
  float s = 0.f;
  for (int d = 0; d < DOUT_; ++d) {
    float v = bf2f(f2bf(C[(size_t)d * NC_ + j]));
    s = fmaf(v, v, s);
  }
  c2[j] = s;
}

// ---------------- pack C (K=448 x N=3136) into B-frag layout ----------------
__global__ void cpack_kernel(const float* __restrict__ C, short* __restrict__ Cpk) {
  int idx = blockIdx.x * 256 + threadIdx.x;       // NCHD_*KCD_*64 = 175616 exact
  int ln = idx & 63;
  int kc = (idx >> 6) % KCD_;
  int nc = idx / (KCD_ * 64);
  int n  = nc * 16 + (ln & 15);
  int k0 = kc * 32 + ((ln >> 4) << 3);
  bh8 o;
#pragma unroll
  for (int j = 0; j < 8; ++j) o[j] = f2bf(C[(size_t)(k0 + j) * NC_ + n]);
  *(bh8*)(Cpk + (size_t)idx * 8) = o;
}

// ---------------- pack W^T (K=1792 x N=448) into B-frag layout ----------------
__global__ void wpack_kernel(const float* __restrict__ W, short* __restrict__ Wpk) {
  int idx = blockIdx.x * 256 + threadIdx.x;       // NCHP_*KCP_*64 = 100352 exact
  int ln = idx & 63;
  int kc = (idx >> 6) % KCP_;
  int nc = idx / (KCP_ * 64);
  int n  = nc * 16 + (ln & 15);
  int k0 = kc * 32 + ((ln >> 4) << 3);
  bh8 o;
#pragma unroll
  for (int j = 0; j < 8; ++j) o[j] = f2bf(W[(size_t)n * DIN_ + k0 + j]);
  *(bh8*)(Wpk + (size_t)idx * 8) = o;
}

// ======== phi: A-frags direct from desc; bias+coords fused; in-place phipack ========
__global__ __launch_bounds__(256) void phi_mfma(
    const short* __restrict__ desc, const short* __restrict__ Wpk,
    const float* __restrict__ cw, const float* __restrict__ cb,
    short* __restrict__ phip /* aliases desc */) {
  __shared__ __align__(16) float Dt[16 * DTS_];   // 28.9 KB
  const int wv = threadIdx.x >> 6, ln = threadIdx.x & 63;
  const int pix0 = blockIdx.x * 32;
  const short* aptr = desc + ((size_t)(pix0 + (ln & 15))) * KD_ + ((ln >> 4) << 3);

  f32x4 acc[2][7];
#pragma unroll
  for (int rc = 0; rc < 2; ++rc)
#pragma unroll
    for (int i = 0; i < 7; ++i) acc[rc][i] = (f32x4){0.f, 0.f, 0.f, 0.f};

  const short* bbase = Wpk + (size_t)(wv * 7) * (KCP_ * 512) + ln * 8;
  for (int kc = 0; kc < KCP_; ++kc) {
    bh8 a0 = *(const bh8*)(aptr + kc * 32);
    bh8 a1 = *(const bh8*)(aptr + 16 * KD_ + kc * 32);
    const short* bp = bbase + kc * 512;
#pragma unroll
    for (int i = 0; i < 7; ++i) {
      bh8 bfr = *(const bh8*)(bp + (size_t)i * (KCP_ * 512));
      acc[0][i] = __builtin_amdgcn_mfma_f32_16x16x32_bf16(a0, bfr, acc[0][i], 0, 0, 0);
      acc[1][i] = __builtin_amdgcn_mfma_f32_16x16x32_bf16(a1, bfr, acc[1][i], 0, 0, 0);
    }
  }

  for (int rc = 0; rc < 2; ++rc) {
    __syncthreads();   // rc=0: all desc reads done; rc=1: all rc=0 repack reads done
#pragma unroll
    for (int i = 0; i < 7; ++i) {
      int col = (wv * 7 + i) * 16 + (ln & 15);
      float bias = cb[col];
      float wx = cw[(size_t)col * DIN_ + 1792];
      float wy = cw[(size_t)col * DIN_ + 1793];
#pragma unroll
      for (int r = 0; r < 4; ++r) {
        int row = ((ln >> 4) << 2) + r;
        int pid = pix0 + rc * 16 + row;
        int hw = pid % HW_;
        int hh = hw / 56, ww = hw % 56;
        float xx = (float)hh * (2.0f / 55.0f) - 1.0f;
        float yy = (float)ww * (2.0f / 55.0f) - 1.0f;
        Dt[row * DTS_ + col] = acc[rc][i][r] + bias + wx * xx + wy * yy;
      }
    }
    __syncthreads();
    short* op = phip + (size_t)(blockIdx.x * 2 + rc) * PCH_;
    for (int item = threadIdx.x; item < KCD_ * 64; item += 256) {
      int kc = item >> 6, lp = item & 63;
      int m = lp & 15, k0 = kc * 32 + ((lp >> 4) << 3);
      bh8 o;
#pragma unroll
      for (int j = 0; j < 8; ++j) o[j] = f2bf(Dt[m * DTS_ + k0 + j]);
      *(bh8*)(op + (size_t)item * 8) = o;
    }
  }
}

// ======== dist v9: fully SCALARIZED state (no arrays -> nothing to spill) ========
// wave = 16 pixels x half-N (49 paired iterations), no LDS, no barrier.
// A-frags: 14 named bh8; top-3: 12 named floats; f2: 4 named floats.
// __launch_bounds__(256,4): 128-VGPR budget >= ~95 live set.
__device__ __forceinline__ void insert3(float& t0, float& t1, float& t2, float v) {
  if (v < t2) {
    if (v < t1) {
      t2 = t1;
      if (v < t0) { t1 = t0; t0 = v; } else t1 = v;
    } else t2 = v;
  }
}
__device__ __forceinline__ void merge3(float& a0, float& a1, float& a2,
                                       float b0, float b1, float b2) {
  float lo0 = fminf(a0, b0), hi0 = fmaxf(a0, b0);
  float lo1 = fminf(a1, b1), hi1 = fmaxf(a1, b1);
  float lo2 = fminf(a2, b2);
  a0 = lo0;
  a1 = fminf(hi0, lo1);
  a2 = fminf(fmaxf(hi0, lo1), fminf(hi1, lo2));
}
__device__ __forceinline__ float sumsq8(bh8 a, float s) {
#pragma unroll
  for (int j = 0; j < 8; ++j) { float v = bf2f(a[j]); s = fmaf(v, v, s); }
  return s;
}

#define AFRAG_LIST(X) X(0) X(1) X(2) X(3) X(4) X(5) X(6) X(7) X(8) X(9) X(10) X(11) X(12) X(13)

__global__ __launch_bounds__(256, 4) void dist_part(
    const short* __restrict__ phip, const short* __restrict__ Cpk,
    const float* __restrict__ c2g, float* __restrict__ part) {
  const int wv = threadIdx.x >> 6, ln = threadIdx.x & 63;
  const int chunk = blockIdx.x * 2 + (wv >> 1);   // 16-pixel chunk
  const int half  = wv & 1;                       // which half of the center bank

  const short* ap = phip + (size_t)chunk * PCH_ + ln * 8;
#define LOADA(i) bh8 A##i = *(const bh8*)(ap + (i) * 512);
  AFRAG_LIST(LOADA)
#undef LOADA

  // f2 per pixel row (self-consistent with bf16 MFMA dot)
  float sum = 0.f;
#define SQ(i) sum = sumsq8(A##i, sum);
  AFRAG_LIST(SQ)
#undef SQ
  sum += __shfl_xor(sum, 16, 64);
  sum += __shfl_xor(sum, 32, 64);
  const int rb = (ln >> 4) << 2;
  float f2r0 = __shfl(sum, rb + 0, 64);
  float f2r1 = __shfl(sum, rb + 1, 64);
  float f2r2 = __shfl(sum, rb + 2, 64);
  float f2r3 = __shfl(sum, rb + 3, 64);

  float t00 = 1e30f, t01 = 1e30f, t02 = 1e30f;
  float t10 = 1e30f, t11 = 1e30f, t12 = 1e30f;
  float t20 = 1e30f, t21 = 1e30f, t22 = 1e30f;
  float t30 = 1e30f, t31 = 1e30f, t32 = 1e30f;

  const int nc0 = half * (NCHD_ / 2);
  const short* bbase = Cpk + (size_t)nc0 * (KCD_ * 512) + ln * 8;
  const float* c2base = c2g + (size_t)nc0 * 16 + (ln & 15);
  for (int i = 0; i < NCHD_ / 4; ++i) {
    const short* bpA = bbase + (size_t)(2 * i) * (KCD_ * 512);
    const short* bpB = bpA + (KCD_ * 512);
    f32x4 accA = {0.f, 0.f, 0.f, 0.f}, accB = {0.f, 0.f, 0.f, 0.f};
#define MF(kc) { \
    bh8 bA = *(const bh8*)(bpA + (kc) * 512); \
    bh8 bB = *(const bh8*)(bpB + (kc) * 512); \
    accA = __builtin_amdgcn_mfma_f32_16x16x32_bf16(A##kc, bA, accA, 0, 0, 0); \
    accB = __builtin_amdgcn_mfma_f32_16x16x32_bf16(A##kc, bB, accB, 0, 0, 0); }
    AFRAG_LIST(MF)
#undef MF
    float c2A = c2base[(size_t)(2 * i) * 16];
    float c2B = c2base[(size_t)(2 * i + 1) * 16];
    insert3(t00, t01, t02, f2r0 + c2A - 2.0f * accA[0]);
    insert3(t10, t11, t12, f2r1 + c2A - 2.0f * accA[1]);
    insert3(t20, t21, t22, f2r2 + c2A - 2.0f * accA[2]);
    insert3(t30, t31, t32, f2r3 + c2A - 2.0f * accA[3]);
    insert3(t00, t01, t02, f2r0 + c2B - 2.0f * accB[0]);
    insert3(t10, t11, t12, f2r1 + c2B - 2.0f * accB[1]);
    insert3(t20, t21, t22, f2r2 + c2B - 2.0f * accB[2]);
    insert3(t30, t31, t32, f2r3 + c2B - 2.0f * accB[3]);
  }

  // merge the 16 column-lanes (same pixel rows, different centers) — shfl only
#pragma unroll
  for (int m = 1; m <= 8; m <<= 1) {
    float b0, b1, b2;
    b0 = __shfl_xor(t00, m, 64); b1 = __shfl_xor(t01, m, 64); b2 = __shfl_xor(t02, m, 64);
    merge3(t00, t01, t02, b0, b1, b2);
    b0 = __shfl_xor(t10, m, 64); b1 = __shfl_xor(t11, m, 64); b2 = __shfl_xor(t12, m, 64);
    merge3(t10, t11, t12, b0, b1, b2);
    b0 = __shfl_xor(t20, m, 64); b1 = __shfl_xor(t21, m, 64); b2 = __shfl_xor(t22, m, 64);
    merge3(t20, t21, t22, b0, b1, b2);
    b0 = __shfl_xor(t30, m, 64); b1 = __shfl_xor(t31, m, 64); b2 = __shfl_xor(t32, m, 64);
    merge3(t30, t31, t32, b0, b1, b2);
  }

  if ((ln & 15) == 0) {
    float* q = part + ((size_t)(chunk * 16 + rb)) * 8 + half * 4;
    q[0] = t00; q[1] = t01; q[2] = t02;
    q[8] = t10; q[9] = t11; q[10] = t12;
    q[16] = t20; q[17] = t21; q[18] = t22;
    q[24] = t30; q[25] = t31; q[26] = t32;
  }
}

// ======== merge: combine 2 partial triples per pixel, softmin score ========
__global__ __launch_bounds__(256) void merge_kernel(const float* __restrict__ part,
                                                    float* __restrict__ out) {
  int p = blockIdx.x * 256 + threadIdx.x;   // 25088 exact
  const float* q = part + (size_t)p * 8;
  float a0 = q[0], a1 = q[1], a2 = q[2];
  merge3(a0, a1, a2, q[4], q[5], q[6]);
  float d0 = sqrtf(fmaxf(a0, 0.f));
  float d1 = sqrtf(fmaxf(a1, 0.f));
  float d2 = sqrtf(fmaxf(a2, 0.f));
  float s0 = 1.0f / (1.0f + expf(d0 - d1) + expf(d0 - d2));
  out[p] = s0 * d0;
}

// ---------------- launch ----------------
extern "C" void kernel_launch(void* const* d_in, const int* in_sizes, int n_in,
                              void* d_out, int out_size, void* d_ws, size_t ws_size,
                              hipStream_t stream) {
  const float* p0 = (const float*)d_in[0];
  const float* p1 = (const float*)d_in[1];
  const float* p2 = (const float*)d_in[2];
  const float* cw = (const float*)d_in[3];
  const float* cb = (const float*)d_in[4];
  const float* C  = (const float*)d_in[5];
  float* out = (float*)d_out;

  short* desc = (short*)d_ws;                                   // 44,957,696 shorts
  short* Cpk  = desc + (size_t)25088 * KD_;                     //  1,404,928 shorts
  short* Wpk  = Cpk + (size_t)NCHD_ * KCD_ * 512;               //    802,816 shorts
  float* c2   = (float*)(Wpk + (size_t)NCHP_ * KCP_ * 512);     //      3,136 floats
  float* part = c2 + NC_;                                       //    200,704 floats (~0.8 MB)

  desc0_kernel<<<dim3(4, 56, 8),  256, 0, stream>>>(p0, desc);
  desc1_kernel<<<dim3(8, 56, 8),  256, 0, stream>>>(p1, desc);
  desc2_kernel<<<dim3(16, 56, 8), 256, 0, stream>>>(p2, desc);
  cent2_kernel<<<(NC_ + 255) / 256, 256, 0, stream>>>(C, c2);
  cpack_kernel<<<NCHD_ * KCD_ * 64 / 256, 256, 0, stream>>>(C, Cpk);
  wpack_kernel<<<NCHP_ * KCP_ * 64 / 256, 256, 0, stream>>>(cw, Wpk);
  phi_mfma<<<25088 / 32, 256, 0, stream>>>(desc, Wpk, cw, cb, desc);
  dist_part<<<25088 / 32, 256, 0, stream>>>(desc, Cpk, c2, part);
  merge_kernel<<<25088 / 256, 256, 0, stream>>>(part, out);
}